// Round 1
// baseline (355.047 us; speedup 1.0000x reference)
//
#include <hip/hip_runtime.h>
#include <hip/hip_bf16.h>
#include <cstdint>
#include <cstddef>

using f32x4 = __attribute__((ext_vector_type(4))) float;
using s16x8 = __attribute__((ext_vector_type(8))) short;
using s16x4 = __attribute__((ext_vector_type(4))) short;

#define DEVINL __device__ __forceinline__

static constexpr int T_LEN  = 2048;
static constexpr int MROWS  = 8192;   // B*T
static constexpr int NCHUNK = 32;     // T / 64

DEVINL float bf2f(short s){
  unsigned u = ((unsigned)(unsigned short)s) << 16;
  return __builtin_bit_cast(float, u);
}
DEVINL short f2bf(float f){
  unsigned u = __builtin_bit_cast(unsigned, f);
  u = (u + 0x7fffu + ((u >> 16) & 1u)) >> 16;
  return (short)(unsigned short)u;
}

// async global->LDS, 16B per lane; LDS dest must be wave-uniform base (+lane*16 implicit)
#define GLOAD16(gp, lp) \
  __builtin_amdgcn_global_load_lds((__attribute__((address_space(1))) void*)(gp), \
                                   (__attribute__((address_space(3))) void*)(lp), 16, 0, 0)

// ---------------- elementwise f32 -> bf16 ----------------
__global__ __launch_bounds__(256) void cvt_f32_bf16(const float* __restrict__ in,
                                                    short* __restrict__ out, int n4){
  int i = blockIdx.x * 256 + threadIdx.x;
  if (i >= n4) return;
  float4 v = ((const float4*)in)[i];
  short4 o;
  o.x = f2bf(v.x); o.y = f2bf(v.y); o.z = f2bf(v.z); o.w = f2bf(v.w);
  ((short4*)out)[i] = o;
}

// ---------------- transpose f32 [R][C] -> bf16 [C][R] ----------------
__global__ __launch_bounds__(256) void tr_w(const float* __restrict__ in,
                                            short* __restrict__ out, int R, int C){
  __shared__ float tile[32][33];
  int c0 = blockIdx.x * 32, r0 = blockIdx.y * 32;
  int tx = threadIdx.x, ty = threadIdx.y;           // (32,8)
  #pragma unroll
  for (int i = 0; i < 4; ++i){
    int r = ty + i * 8;
    tile[r][tx] = in[(size_t)(r0 + r) * C + c0 + tx];
  }
  __syncthreads();
  #pragma unroll
  for (int i = 0; i < 4; ++i){
    int c = ty + i * 8;
    out[(size_t)(c0 + c) * R + r0 + tx] = f2bf(tile[tx][c]);
  }
}

// ------- transpose bf16 k [8192][1024] -> kT [1024][8192], baking dec_k = gamma^(63-j) -------
__global__ __launch_bounds__(256) void tr_k_decay(const short* __restrict__ in,
                                                  short* __restrict__ out){
  __shared__ float tile[32][33];
  int c0 = blockIdx.x * 32, r0 = blockIdx.y * 32;   // c over 1024 feature cols, r over 8192 rows
  int tx = threadIdx.x, ty = threadIdx.y;
  #pragma unroll
  for (int i = 0; i < 4; ++i){
    int r = ty + i * 8;
    tile[r][tx] = bf2f(in[(size_t)(r0 + r) * 1024 + c0 + tx]);
  }
  __syncthreads();
  #pragma unroll
  for (int i = 0; i < 4; ++i){
    int c  = c0 + ty + i * 8;
    int h  = c >> 7;
    float lg = log2f(1.0f - exp2f(-(float)(5 + h)));
    int srow = r0 + tx;
    int j = srow & 63;
    float dec = exp2f((float)(63 - j) * lg);
    out[(size_t)c * MROWS + srow] = f2bf(tile[tx][ty + i * 8] * dec);
  }
}

// ---------------- RoPE in-place on bf16 [8192][1024], pairs (d, d+64) per head ----------------
__global__ __launch_bounds__(256) void rope_inplace(short* __restrict__ qk, float scale){
  int idx = blockIdx.x * 256 + threadIdx.x;         // 8192 * 512 threads
  int bt  = idx >> 9, rem = idx & 511;
  int h   = rem >> 6, d = rem & 63;
  int t   = bt & (T_LEN - 1);
  float inv = exp2f(-(float)d * (13.287712379549449f / 64.0f));  // 10000^(-d/64)
  float f = (float)t * inv;
  float s, c;
  sincosf(f, &s, &c);
  size_t base = (size_t)bt * 1024 + h * 128 + d;
  float x1 = bf2f(qk[base]), x2 = bf2f(qk[base + 64]);
  qk[base]      = f2bf((x1 * c - x2 * s) * scale);
  qk[base + 64] = f2bf((x2 * c + x1 * s) * scale);
}

// ---------------- 128x128x(BK=64) bt-GEMM: C[m][n] = sum_k A[m][k]*Bt[n][k] ----------------
// MODE 0: bf16 row-major out [M][N]; MODE 1: bf16 transposed out [N][MROWS]; MODE 2: f32 out [M][N]
template<int MODE>
__global__ __launch_bounds__(256) void gemm_bt(const short* __restrict__ A,
                                               const short* __restrict__ Bt,
                                               void* __restrict__ out, int K, int N){
  __shared__ alignas(16) short As[128 * 64];
  __shared__ alignas(16) short Bs[128 * 64];
  const int tid = threadIdx.x, wave = tid >> 6, lane = tid & 63;
  const int m0 = blockIdx.x * 128, n0 = blockIdx.y * 128;
  const int wm = (wave & 1) * 64, wn = (wave >> 1) * 64;
  f32x4 acc[4][4] = {};
  const int srow = wave * 8 + (lane >> 3);          // staging row-in-call (rows are 128B)
  const int sc   = lane & 7;                        // staging 16B-chunk within row
  const int kT = K >> 6;
  for (int kt = 0; kt < kT; ++kt){
    const int k0 = kt << 6;
    #pragma unroll
    for (int c = 0; c < 4; ++c){
      int row = c * 32 + srow;
      int gc  = sc ^ (row & 7);                     // pre-swizzled global source
      GLOAD16(A  + (size_t)(m0 + row) * K + k0 + gc * 8, &As[c * 2048 + wave * 512]);
      GLOAD16(Bt + (size_t)(n0 + row) * K + k0 + gc * 8, &Bs[c * 2048 + wave * 512]);
    }
    __syncthreads();
    #pragma unroll
    for (int ks = 0; ks < 2; ++ks){
      s16x8 af[4], bfr[4];
      #pragma unroll
      for (int mf = 0; mf < 4; ++mf){
        int row = wm + mf * 16 + (lane & 15);
        int ch  = (ks * 4 + (lane >> 4)) ^ (row & 7);
        af[mf] = *(const s16x8*)&As[row * 64 + ch * 8];
      }
      #pragma unroll
      for (int nf = 0; nf < 4; ++nf){
        int row = wn + nf * 16 + (lane & 15);
        int ch  = (ks * 4 + (lane >> 4)) ^ (row & 7);
        bfr[nf] = *(const s16x8*)&Bs[row * 64 + ch * 8];
      }
      #pragma unroll
      for (int mf = 0; mf < 4; ++mf)
        #pragma unroll
        for (int nf = 0; nf < 4; ++nf)
          acc[mf][nf] = __builtin_amdgcn_mfma_f32_16x16x32_bf16(af[mf], bfr[nf], acc[mf][nf], 0, 0, 0);
    }
    __syncthreads();
  }
  #pragma unroll
  for (int mf = 0; mf < 4; ++mf){
    #pragma unroll
    for (int nf = 0; nf < 4; ++nf){
      int col   = n0 + wn + nf * 16 + (lane & 15);
      int rbase = m0 + wm + mf * 16 + 4 * (lane >> 4);
      f32x4 v = acc[mf][nf];
      if (MODE == 0){
        short* o = (short*)out;
        #pragma unroll
        for (int r = 0; r < 4; ++r) o[(size_t)(rbase + r) * N + col] = f2bf(v[r]);
      } else if (MODE == 1){
        short* o = (short*)out;
        s16x4 pk; pk[0] = f2bf(v[0]); pk[1] = f2bf(v[1]); pk[2] = f2bf(v[2]); pk[3] = f2bf(v[3]);
        *(s16x4*)&o[(size_t)col * MROWS + rbase] = pk;
      } else {
        float* o = (float*)out;
        #pragma unroll
        for (int r = 0; r < 4; ++r) o[(size_t)(rbase + r) * N + col] = v[r];
      }
    }
  }
}

// ---------------- retention intra-chunk: o_intra = (mask .* q k^T) v  ----------------
// grid (n=32, h=8, b=4); 256 thr. q,k row-major bf16 [8192][1024]; vT [2048][8192]; o f32 [8192][2048]
__global__ __launch_bounds__(256) void ret_intra(const short* __restrict__ q,
                                                 const short* __restrict__ k,
                                                 const short* __restrict__ vT,
                                                 float* __restrict__ o){
  __shared__ alignas(16) short qs[64 * 128];
  __shared__ alignas(16) short ks_[64 * 128];
  __shared__ alignas(16) short vs[256 * 64];
  __shared__ alignas(16) short ps[64 * 72];         // P[i][j], +8 pad
  const int tid = threadIdx.x, wave = tid >> 6, lane = tid & 63;
  const int n = blockIdx.x, h = blockIdx.y, b = blockIdx.z;
  const size_t rowbase = (size_t)(b * T_LEN + n * 64);
  { // stage q,k: 64 rows x 256B; 4 calls, wave covers 4 rows/call
    int row = wave * 4 + (lane >> 4);
    int scc = lane & 15;
    #pragma unroll
    for (int c = 0; c < 4; ++c){
      int r  = c * 16 + row;
      int gc = scc ^ (r & 7);
      GLOAD16(q + (rowbase + r) * 1024 + h * 128 + gc * 8, &qs [c * 2048 + wave * 512]);
      GLOAD16(k + (rowbase + r) * 1024 + h * 128 + gc * 8, &ks_[c * 2048 + wave * 512]);
    }
  }
  { // stage vT chunk: 256 e-rows x 128B; 8 calls, wave covers 8 rows/call
    int row = wave * 8 + (lane >> 3);
    int scc = lane & 7;
    #pragma unroll
    for (int c = 0; c < 8; ++c){
      int e  = c * 32 + row;
      int gc = scc ^ (e & 7);
      GLOAD16(vT + (size_t)(h * 256 + e) * MROWS + rowbase + gc * 8, &vs[c * 2048 + wave * 512]);
    }
  }
  __syncthreads();
  const float lg = log2f(1.0f - exp2f(-(float)(5 + h)));
  // P^T = k q^T : D1[j][i]; wave owns j in [16w,16w+16)
  f32x4 acc1[4] = {};
  #pragma unroll
  for (int ks = 0; ks < 4; ++ks){
    int rowA = wave * 16 + (lane & 15);
    int chA  = (ks * 4 + (lane >> 4)) ^ (rowA & 7);
    s16x8 af = *(const s16x8*)&ks_[rowA * 128 + chA * 8];
    #pragma unroll
    for (int nf = 0; nf < 4; ++nf){
      int rowB = nf * 16 + (lane & 15);
      int chB  = (ks * 4 + (lane >> 4)) ^ (rowB & 7);
      s16x8 bfr = *(const s16x8*)&qs[rowB * 128 + chB * 8];
      acc1[nf] = __builtin_amdgcn_mfma_f32_16x16x32_bf16(af, bfr, acc1[nf], 0, 0, 0);
    }
  }
  // mask (i>=j: gamma^(i-j)) and store P[i][j] (lane's 4 values are j-consecutive)
  #pragma unroll
  for (int nf = 0; nf < 4; ++nf){
    int i  = nf * 16 + (lane & 15);
    int jb = wave * 16 + 4 * (lane >> 4);
    s16x4 pk;
    #pragma unroll
    for (int r = 0; r < 4; ++r){
      int j = jb + r;
      float val = (i >= j) ? acc1[nf][r] * exp2f((float)(i - j) * lg) : 0.0f;
      pk[r] = f2bf(val);
    }
    *(s16x4*)&ps[i * 72 + jb] = pk;
  }
  __syncthreads();
  // o_intra = P v ; wave owns e in [64w, 64w+64)
  f32x4 acc2[4][4] = {};
  #pragma unroll
  for (int ks = 0; ks < 2; ++ks){
    s16x8 af[4], bfr[4];
    #pragma unroll
    for (int mf = 0; mf < 4; ++mf){
      int i = mf * 16 + (lane & 15);
      af[mf] = *(const s16x8*)&ps[i * 72 + ks * 32 + (lane >> 4) * 8];
    }
    #pragma unroll
    for (int nf = 0; nf < 4; ++nf){
      int e  = wave * 64 + nf * 16 + (lane & 15);
      int ch = (ks * 4 + (lane >> 4)) ^ (e & 7);
      bfr[nf] = *(const s16x8*)&vs[e * 64 + ch * 8];
    }
    #pragma unroll
    for (int mf = 0; mf < 4; ++mf)
      #pragma unroll
      for (int nf = 0; nf < 4; ++nf)
        acc2[mf][nf] = __builtin_amdgcn_mfma_f32_16x16x32_bf16(af[mf], bfr[nf], acc2[mf][nf], 0, 0, 0);
  }
  #pragma unroll
  for (int mf = 0; mf < 4; ++mf){
    #pragma unroll
    for (int nf = 0; nf < 4; ++nf){
      int e  = wave * 64 + nf * 16 + (lane & 15);
      int ib = mf * 16 + 4 * (lane >> 4);
      #pragma unroll
      for (int r = 0; r < 4; ++r)
        o[(rowbase + ib + r) * 2048 + h * 256 + e] = acc2[mf][nf][r];
    }
  }
}

// ---------------- retention inter-chunk (recurrent): state S in MFMA accumulators ----------------
// grid (eblk=4, h=8, b=4); 256 thr. Per block: S[:,e0:e0+64] (128x64 f32 regs across 4 waves).
__global__ __launch_bounds__(256) void ret_inter(const short* __restrict__ q,
                                                 const short* __restrict__ kT,
                                                 const short* __restrict__ vT,
                                                 float* __restrict__ o){
  __shared__ alignas(16) short qs [64 * 128];
  __shared__ alignas(16) short kts[128 * 64];       // kT_dec [d][j]
  __shared__ alignas(16) short vts[64 * 64];        // vT [e][j]
  __shared__ alignas(16) short sts[64 * 136];       // S^T bf16 [e][d], +8 pad
  const int tid = threadIdx.x, wave = tid >> 6, lane = tid & 63;
  const int eb = blockIdx.x, h = blockIdx.y, b = blockIdx.z;
  const int e0 = eb * 64;
  const float lg = log2f(1.0f - exp2f(-(float)(5 + h)));
  const float gC = exp2f(64.0f * lg);
  const int ib = wave * 16 + 4 * (lane >> 4);       // o_inter row base for this thread
  float dq[4];
  #pragma unroll
  for (int r = 0; r < 4; ++r) dq[r] = exp2f((float)(ib + r + 1) * lg);
  f32x4 Sacc[2][4] = {};                            // wave owns d in [32w, 32w+32)
  for (int n = 0; n < NCHUNK; ++n){
    const size_t rowbase = (size_t)(b * T_LEN + n * 64);
    { // stage q (4 calls)
      int row = wave * 4 + (lane >> 4);
      int scc = lane & 15;
      #pragma unroll
      for (int c = 0; c < 4; ++c){
        int r  = c * 16 + row;
        int gc = scc ^ (r & 7);
        GLOAD16(q + (rowbase + r) * 1024 + h * 128 + gc * 8, &qs[c * 2048 + wave * 512]);
      }
    }
    { // stage kT_dec [128][64] (4 calls) and vT [64][64] (2 calls)
      int row = wave * 8 + (lane >> 3);
      int scc = lane & 7;
      #pragma unroll
      for (int c = 0; c < 4; ++c){
        int d  = c * 32 + row;
        int gc = scc ^ (d & 7);
        GLOAD16(kT + (size_t)(h * 128 + d) * MROWS + rowbase + gc * 8, &kts[c * 2048 + wave * 512]);
      }
      #pragma unroll
      for (int c = 0; c < 2; ++c){
        int e  = c * 32 + row;
        int gc = scc ^ (e & 7);
        GLOAD16(vT + (size_t)(h * 256 + e0 + e) * MROWS + rowbase + gc * 8, &vts[c * 2048 + wave * 512]);
      }
    }
    // write S^T (bf16) snapshot of current state
    #pragma unroll
    for (int mf = 0; mf < 2; ++mf){
      #pragma unroll
      for (int nf = 0; nf < 4; ++nf){
        int e  = nf * 16 + (lane & 15);
        int db = wave * 32 + mf * 16 + 4 * (lane >> 4);
        s16x4 pk;
        #pragma unroll
        for (int r = 0; r < 4; ++r) pk[r] = f2bf(Sacc[mf][nf][r]);
        *(s16x4*)&sts[e * 136 + db] = pk;
      }
    }
    __syncthreads();
    // o_inter = (q S) * dec_q ; wave owns i in [16w,16w+16)
    f32x4 acc3[4] = {};
    #pragma unroll
    for (int ks = 0; ks < 4; ++ks){
      int rowA = wave * 16 + (lane & 15);
      int chA  = (ks * 4 + (lane >> 4)) ^ (rowA & 7);
      s16x8 af = *(const s16x8*)&qs[rowA * 128 + chA * 8];
      #pragma unroll
      for (int nf = 0; nf < 4; ++nf){
        int e = nf * 16 + (lane & 15);
        s16x8 bfr = *(const s16x8*)&sts[e * 136 + ks * 32 + (lane >> 4) * 8];
        acc3[nf] = __builtin_amdgcn_mfma_f32_16x16x32_bf16(af, bfr, acc3[nf], 0, 0, 0);
      }
    }
    #pragma unroll
    for (int nf = 0; nf < 4; ++nf){
      int e = e0 + nf * 16 + (lane & 15);
      #pragma unroll
      for (int r = 0; r < 4; ++r){
        size_t idx = (rowbase + ib + r) * 2048 + h * 256 + e;
        o[idx] += acc3[nf][r] * dq[r];
      }
    }
    // S = gC*S + kdec^T v
    #pragma unroll
    for (int mf = 0; mf < 2; ++mf)
      #pragma unroll
      for (int nf = 0; nf < 4; ++nf)
        #pragma unroll
        for (int r = 0; r < 4; ++r) Sacc[mf][nf][r] *= gC;
    #pragma unroll
    for (int ks = 0; ks < 2; ++ks){
      s16x8 af2[2], bf2v[4];
      #pragma unroll
      for (int mf = 0; mf < 2; ++mf){
        int d  = wave * 32 + mf * 16 + (lane & 15);
        int ch = (ks * 4 + (lane >> 4)) ^ (d & 7);
        af2[mf] = *(const s16x8*)&kts[d * 64 + ch * 8];
      }
      #pragma unroll
      for (int nf = 0; nf < 4; ++nf){
        int e  = nf * 16 + (lane & 15);
        int ch = (ks * 4 + (lane >> 4)) ^ (e & 7);
        bf2v[nf] = *(const s16x8*)&vts[e * 64 + ch * 8];
      }
      #pragma unroll
      for (int mf = 0; mf < 2; ++mf)
        #pragma unroll
        for (int nf = 0; nf < 4; ++nf)
          Sacc[mf][nf] = __builtin_amdgcn_mfma_f32_16x16x32_bf16(af2[mf], bf2v[nf], Sacc[mf][nf], 0, 0, 0);
    }
    __syncthreads();
  }
}

// ---------------- RMS-norm over DV=256 + SiLU gate: y = o/rms * nw * g*sigmoid(g) ----------------
__global__ __launch_bounds__(256) void fuse_norm_gate(const float* __restrict__ o,
                                                      const short* __restrict__ g,
                                                      const float* __restrict__ nw,
                                                      short* __restrict__ y){
  int bt  = blockIdx.x;
  int tid = threadIdx.x;
  int h = tid >> 5, sub = tid & 31;                 // 32 lanes per head, 8 elems each
  size_t base = (size_t)bt * 2048 + h * 256 + sub * 8;
  float4 a  = *(const float4*)&o[base];
  float4 b2 = *(const float4*)&o[base + 4];
  float vals[8] = {a.x, a.y, a.z, a.w, b2.x, b2.y, b2.z, b2.w};
  float ss = 0.f;
  #pragma unroll
  for (int j = 0; j < 8; ++j) ss += vals[j] * vals[j];
  #pragma unroll
  for (int off = 16; off >= 1; off >>= 1) ss += __shfl_xor(ss, off, 64);
  float rr = 1.0f / sqrtf(ss * (1.0f / 256.0f) + 1e-5f);
  s16x8 gv = *(const s16x8*)&g[base];
  s16x8 yo;
  #pragma unroll
  for (int j = 0; j < 8; ++j){
    float gf  = bf2f(gv[j]);
    float sig = 1.0f / (1.0f + expf(-gf));
    yo[j] = f2bf(vals[j] * rr * nw[sub * 8 + j] * gf * sig);
  }
  *(s16x8*)&y[base] = yo;
}

// ---------------- host ----------------
extern "C" void kernel_launch(void* const* d_in, const int* in_sizes, int n_in,
                              void* d_out, int out_size, void* d_ws, size_t ws_size,
                              hipStream_t stream){
  const float* x  = (const float*)d_in[0];
  const float* Wq = (const float*)d_in[1];
  const float* Wk = (const float*)d_in[2];
  const float* Wv = (const float*)d_in[3];
  const float* Wg = (const float*)d_in[4];
  const float* Wo = (const float*)d_in[5];
  const float* nw = (const float*)d_in[6];
  float* out = (float*)d_out;

  // workspace layout (208.8 MB). yb aliases [0,32MB) = xb+WT+head of qb — all dead before fuse.
  char* w = (char*)d_ws;
  short* xb  = (short*)w;               w += (size_t)8192 * 1024 * 2;   // 16 MB
  short* WT  = (short*)w;               w += (size_t)6144 * 1024 * 2;   // 12.6 MB (WqT|WkT|WvT|WgT)
  short* qb  = (short*)w;               w += (size_t)8192 * 1024 * 2;   // 16 MB
  short* kb  = (short*)w;               w += (size_t)8192 * 1024 * 2;   // 16 MB
  short* kTt = (short*)w;               w += (size_t)1024 * 8192 * 2;   // 16 MB
  short* vT  = (short*)w;               w += (size_t)2048 * 8192 * 2;   // 32 MB
  short* gb  = (short*)w;               w += (size_t)8192 * 2048 * 2;   // 32 MB
  float* ob  = (float*)w;               w += (size_t)8192 * 2048 * 4;   // 64 MB
  short* WoT = (short*)w;               w += (size_t)1024 * 2048 * 2;   // 4 MB
  short* yb  = (short*)d_ws;                                            // alias, 32 MB

  cvt_f32_bf16<<<8192, 256, 0, stream>>>(x, xb, 8192 * 1024 / 4);
  dim3 tb(32, 8);
  tr_w<<<dim3(32, 32), tb, 0, stream>>>(Wq, WT,                       1024, 1024);
  tr_w<<<dim3(32, 32), tb, 0, stream>>>(Wk, WT + (size_t)1024 * 1024, 1024, 1024);
  tr_w<<<dim3(64, 32), tb, 0, stream>>>(Wv, WT + (size_t)2048 * 1024, 1024, 2048);
  tr_w<<<dim3(64, 32), tb, 0, stream>>>(Wg, WT + (size_t)4096 * 1024, 1024, 2048);
  tr_w<<<dim3(32, 64), tb, 0, stream>>>(Wo, WoT,                      2048, 1024);

  gemm_bt<0><<<dim3(64,  8), 256, 0, stream>>>(xb, WT,                       qb, 1024, 1024);
  gemm_bt<0><<<dim3(64,  8), 256, 0, stream>>>(xb, WT + (size_t)1024 * 1024, kb, 1024, 1024);
  gemm_bt<1><<<dim3(64, 16), 256, 0, stream>>>(xb, WT + (size_t)2048 * 1024, vT, 1024, 2048);
  gemm_bt<0><<<dim3(64, 16), 256, 0, stream>>>(xb, WT + (size_t)4096 * 1024, gb, 1024, 2048);

  rope_inplace<<<16384, 256, 0, stream>>>(qb, 0.08838834764831845f);  // DK^-0.5
  rope_inplace<<<16384, 256, 0, stream>>>(kb, 1.0f);
  tr_k_decay<<<dim3(32, 256), tb, 0, stream>>>(kb, kTt);

  ret_intra<<<dim3(32, 8, 4), 256, 0, stream>>>(qb, kb, vT, ob);
  ret_inter<<<dim3(4, 8, 4),  256, 0, stream>>>(qb, kTt, vT, ob);
  fuse_norm_gate<<<8192, 256, 0, stream>>>(ob, gb, nw, yb);
  gemm_bt<2><<<dim3(64, 8), 256, 0, stream>>>(yb, WoT, out, 2048, 1024);
}

// Round 2
// 346.113 us; speedup vs baseline: 1.0258x; 1.0258x over previous
//
#include <hip/hip_runtime.h>
#include <hip/hip_bf16.h>
#include <cstdint>
#include <cstddef>

using f32x4 = __attribute__((ext_vector_type(4))) float;
using s16x8 = __attribute__((ext_vector_type(8))) short;
using s16x4 = __attribute__((ext_vector_type(4))) short;

#define DEVINL __device__ __forceinline__

static constexpr int T_LEN  = 2048;
static constexpr int MROWS  = 8192;   // B*T
static constexpr int NCHUNK = 32;     // T / 64

DEVINL float bf2f(short s){
  unsigned u = ((unsigned)(unsigned short)s) << 16;
  return __builtin_bit_cast(float, u);
}
DEVINL short f2bf(float f){
  unsigned u = __builtin_bit_cast(unsigned, f);
  u = (u + 0x7fffu + ((u >> 16) & 1u)) >> 16;
  return (short)(unsigned short)u;
}

// async global->LDS, 16B per lane; LDS dest must be wave-uniform base (+lane*16 implicit)
#define GLOAD16(gp, lp) \
  __builtin_amdgcn_global_load_lds((__attribute__((address_space(1))) void*)(gp), \
                                   (__attribute__((address_space(3))) void*)(lp), 16, 0, 0)

// ---------------- elementwise f32 -> bf16 ----------------
__global__ __launch_bounds__(256) void cvt_f32_bf16(const float* __restrict__ in,
                                                    short* __restrict__ out, int n4){
  int i = blockIdx.x * 256 + threadIdx.x;
  if (i >= n4) return;
  float4 v = ((const float4*)in)[i];
  short4 o;
  o.x = f2bf(v.x); o.y = f2bf(v.y); o.z = f2bf(v.z); o.w = f2bf(v.w);
  ((short4*)out)[i] = o;
}

// ---------------- transpose f32 [R][C] -> bf16 [C][R] ----------------
__global__ __launch_bounds__(256) void tr_w(const float* __restrict__ in,
                                            short* __restrict__ out, int R, int C){
  __shared__ float tile[32][33];
  int c0 = blockIdx.x * 32, r0 = blockIdx.y * 32;
  int tx = threadIdx.x, ty = threadIdx.y;           // (32,8)
  #pragma unroll
  for (int i = 0; i < 4; ++i){
    int r = ty + i * 8;
    tile[r][tx] = in[(size_t)(r0 + r) * C + c0 + tx];
  }
  __syncthreads();
  #pragma unroll
  for (int i = 0; i < 4; ++i){
    int c = ty + i * 8;
    out[(size_t)(c0 + c) * R + r0 + tx] = f2bf(tile[tx][c]);
  }
}

// ------- transpose bf16 k [8192][1024] -> kT [1024][8192], baking dec_k = gamma^(63-j) -------
__global__ __launch_bounds__(256) void tr_k_decay(const short* __restrict__ in,
                                                  short* __restrict__ out){
  __shared__ float tile[32][33];
  int c0 = blockIdx.x * 32, r0 = blockIdx.y * 32;   // c over 1024 feature cols, r over 8192 rows
  int tx = threadIdx.x, ty = threadIdx.y;
  #pragma unroll
  for (int i = 0; i < 4; ++i){
    int r = ty + i * 8;
    tile[r][tx] = bf2f(in[(size_t)(r0 + r) * 1024 + c0 + tx]);
  }
  __syncthreads();
  #pragma unroll
  for (int i = 0; i < 4; ++i){
    int c  = c0 + ty + i * 8;
    int h  = c >> 7;
    float lg = log2f(1.0f - exp2f(-(float)(5 + h)));
    int srow = r0 + tx;
    int j = srow & 63;
    float dec = exp2f((float)(63 - j) * lg);
    out[(size_t)c * MROWS + srow] = f2bf(tile[tx][ty + i * 8] * dec);
  }
}

// ------- RoPE in-place on bf16 [8192][1024]; optional dec_q = gamma^((t%64)+1) bake (q only) -------
__global__ __launch_bounds__(256) void rope_inplace(short* __restrict__ qk, float scale, int bake){
  int idx = blockIdx.x * 256 + threadIdx.x;         // 8192 * 512 threads
  int bt  = idx >> 9, rem = idx & 511;
  int h   = rem >> 6, d = rem & 63;
  int t   = bt & (T_LEN - 1);
  float inv = exp2f(-(float)d * (13.287712379549449f / 64.0f));  // 10000^(-d/64)
  float f = (float)t * inv;
  float s, c;
  sincosf(f, &s, &c);
  float mult = scale;
  if (bake){
    float lg = log2f(1.0f - exp2f(-(float)(5 + h)));
    mult *= exp2f((float)((t & 63) + 1) * lg);      // gamma^(i+1)
  }
  size_t base = (size_t)bt * 1024 + h * 128 + d;
  float x1 = bf2f(qk[base]), x2 = bf2f(qk[base + 64]);
  qk[base]      = f2bf((x1 * c - x2 * s) * mult);
  qk[base + 64] = f2bf((x2 * c + x1 * s) * mult);
}

// ---------------- 128x128x(BK=64) bt-GEMM: C[m][n] = sum_k A[m][k]*Bt[n][k] ----------------
// MODE 0: bf16 row-major out [M][N]; MODE 1: bf16 transposed out [N][MROWS]; MODE 2: f32 out [M][N]
template<int MODE>
__global__ __launch_bounds__(256) void gemm_bt(const short* __restrict__ A,
                                               const short* __restrict__ Bt,
                                               void* __restrict__ out, int K, int N){
  __shared__ alignas(16) short As[128 * 64];
  __shared__ alignas(16) short Bs[128 * 64];
  const int tid = threadIdx.x, wave = tid >> 6, lane = tid & 63;
  const int m0 = blockIdx.x * 128, n0 = blockIdx.y * 128;
  const int wm = (wave & 1) * 64, wn = (wave >> 1) * 64;
  f32x4 acc[4][4] = {};
  const int srow = wave * 8 + (lane >> 3);          // staging row-in-call (rows are 128B)
  const int sc   = lane & 7;                        // staging 16B-chunk within row
  const int kT = K >> 6;
  for (int kt = 0; kt < kT; ++kt){
    const int k0 = kt << 6;
    #pragma unroll
    for (int c = 0; c < 4; ++c){
      int row = c * 32 + srow;
      int gc  = sc ^ (row & 7);                     // pre-swizzled global source
      GLOAD16(A  + (size_t)(m0 + row) * K + k0 + gc * 8, &As[c * 2048 + wave * 512]);
      GLOAD16(Bt + (size_t)(n0 + row) * K + k0 + gc * 8, &Bs[c * 2048 + wave * 512]);
    }
    __syncthreads();
    #pragma unroll
    for (int ks = 0; ks < 2; ++ks){
      s16x8 af[4], bfr[4];
      #pragma unroll
      for (int mf = 0; mf < 4; ++mf){
        int row = wm + mf * 16 + (lane & 15);
        int ch  = (ks * 4 + (lane >> 4)) ^ (row & 7);
        af[mf] = *(const s16x8*)&As[row * 64 + ch * 8];
      }
      #pragma unroll
      for (int nf = 0; nf < 4; ++nf){
        int row = wn + nf * 16 + (lane & 15);
        int ch  = (ks * 4 + (lane >> 4)) ^ (row & 7);
        bfr[nf] = *(const s16x8*)&Bs[row * 64 + ch * 8];
      }
      #pragma unroll
      for (int mf = 0; mf < 4; ++mf)
        #pragma unroll
        for (int nf = 0; nf < 4; ++nf)
          acc[mf][nf] = __builtin_amdgcn_mfma_f32_16x16x32_bf16(af[mf], bfr[nf], acc[mf][nf], 0, 0, 0);
    }
    __syncthreads();
  }
  #pragma unroll
  for (int mf = 0; mf < 4; ++mf){
    #pragma unroll
    for (int nf = 0; nf < 4; ++nf){
      int col   = n0 + wn + nf * 16 + (lane & 15);
      int rbase = m0 + wm + mf * 16 + 4 * (lane >> 4);
      f32x4 v = acc[mf][nf];
      if (MODE == 0){
        short* o = (short*)out;
        #pragma unroll
        for (int r = 0; r < 4; ++r) o[(size_t)(rbase + r) * N + col] = f2bf(v[r]);
      } else if (MODE == 1){
        short* o = (short*)out;
        s16x4 pk; pk[0] = f2bf(v[0]); pk[1] = f2bf(v[1]); pk[2] = f2bf(v[2]); pk[3] = f2bf(v[3]);
        *(s16x4*)&o[(size_t)col * MROWS + rbase] = pk;
      } else {
        float* o = (float*)out;
        #pragma unroll
        for (int r = 0; r < 4; ++r) o[(size_t)(rbase + r) * N + col] = v[r];
      }
    }
  }
}

// ---------------- retention state scan: S in MFMA accumulators, write bf16 ST[n] snapshots ----------------
// grid (8=db*eb, 8, 4); 256 thr. Block owns d-range 64 (db) x e-range 64 (eb).
// Triple-buffered LDS, 2-deep prefetch, counted vmcnt (loads stay in flight across barriers).
__global__ __launch_bounds__(256) void ret_scan(const short* __restrict__ kT,
                                                const short* __restrict__ vT,
                                                short* __restrict__ ST){
  __shared__ alignas(16) short kbuf[3][4096];
  __shared__ alignas(16) short vbuf[3][4096];
  const int tid = threadIdx.x, wave = tid >> 6, lane = tid & 63;
  const int db = blockIdx.x & 1, eb = blockIdx.x >> 1;
  const int h = blockIdx.y, b = blockIdx.z;
  const int d0 = db * 64, e0 = eb * 64;
  const float lg = log2f(1.0f - exp2f(-(float)(5 + h)));
  const float gC = exp2f(64.0f * lg);
  f32x4 Sacc[4] = {};
  const int srow = wave * 8 + (lane >> 3);
  const int sc   = lane & 7;

  auto STAGE = [&](int n, int buf){
    size_t rowbase = (size_t)(b * T_LEN + n * 64);
    #pragma unroll
    for (int c = 0; c < 2; ++c){
      int r = c * 32 + srow;
      int gc = sc ^ (r & 7);
      GLOAD16(kT + (size_t)(h * 128 + d0 + r) * MROWS + rowbase + gc * 8,
              &kbuf[buf][c * 2048 + wave * 512]);
    }
    #pragma unroll
    for (int c = 0; c < 2; ++c){
      int r = c * 32 + srow;
      int gc = sc ^ (r & 7);
      GLOAD16(vT + (size_t)(h * 256 + e0 + r) * MROWS + rowbase + gc * 8,
              &vbuf[buf][c * 2048 + wave * 512]);
    }
  };

  STAGE(0, 0);
  STAGE(1, 1);
  for (int n = 0; n < NCHUNK; ++n){
    const int buf = n % 3;
    if (n + 2 < NCHUNK) STAGE(n + 2, (n + 2) % 3);      // 4 loads
    if (n > 0){                                          // 4 stores (snapshot BEFORE this chunk)
      size_t stb = (((size_t)n * 4 + b) * 8 + h) * 32768;
      int dbase = d0 + 16 * wave + 4 * (lane >> 4);
      #pragma unroll
      for (int nf = 0; nf < 4; ++nf){
        int e = e0 + nf * 16 + (lane & 15);
        s16x4 pk;
        #pragma unroll
        for (int r = 0; r < 4; ++r) pk[r] = f2bf(Sacc[nf][r]);
        *(s16x4*)&ST[stb + (size_t)e * 128 + dbase] = pk;
      }
    }
    // counted vmcnt: guarantee chunk-n loads complete; newer loads/stores stay outstanding
    if (n == 0)       asm volatile("s_waitcnt vmcnt(8)"  ::: "memory");
    else if (n < 30)  asm volatile("s_waitcnt vmcnt(12)" ::: "memory");
    else if (n == 30) asm volatile("s_waitcnt vmcnt(8)"  ::: "memory");
    else              asm volatile("s_waitcnt vmcnt(4)"  ::: "memory");
    __builtin_amdgcn_s_barrier();
    __builtin_amdgcn_sched_barrier(0);
    #pragma unroll
    for (int nf = 0; nf < 4; ++nf)
      #pragma unroll
      for (int r = 0; r < 4; ++r) Sacc[nf][r] *= gC;
    #pragma unroll
    for (int ks = 0; ks < 2; ++ks){
      int d = 16 * wave + (lane & 15);
      int chA = (ks * 4 + (lane >> 4)) ^ (d & 7);
      s16x8 af = *(const s16x8*)&kbuf[buf][d * 64 + chA * 8];
      #pragma unroll
      for (int nf = 0; nf < 4; ++nf){
        int e = nf * 16 + (lane & 15);
        int chB = (ks * 4 + (lane >> 4)) ^ (e & 7);
        s16x8 bv = *(const s16x8*)&vbuf[buf][e * 64 + chB * 8];
        Sacc[nf] = __builtin_amdgcn_mfma_f32_16x16x32_bf16(af, bv, Sacc[nf], 0, 0, 0);
      }
    }
    __builtin_amdgcn_s_barrier();
    __builtin_amdgcn_sched_barrier(0);
  }
}

// ---------------- fused per-chunk retention + RMS-norm + SiLU gate ----------------
// grid (n=32, h=8, b=4); 256 thr. o = q'.S_n + (mask.*q'k^T).v ; y = o/rms*nw*g*sig(g) (bf16)
// q' has DK^-0.5, rope, and gamma^(i+1) baked; mask multiplier is gamma^(-(j+1)).
__global__ __launch_bounds__(256) void ret_fused(const short* __restrict__ q,
                                                 const short* __restrict__ k,
                                                 const short* __restrict__ vT,
                                                 const short* __restrict__ ST,
                                                 const short* __restrict__ g,
                                                 const float* __restrict__ nw,
                                                 short* __restrict__ y){
  __shared__ alignas(16) short L[70656];              // 138 KiB
  short* QS  = L;                                     // 8192  (64x128)
  short* KS  = L + 8192;                              // 8192  (64x128)
  short* VS  = L + 16384;                             // 16384 (256x64)
  short* STS = L + 32768;                             // 32768 (256x128)
  short* PS  = L + 65536;                             // 4608  (64x72)
  float* SS  = (float*)(L + 70144);                   // 256 f32
  short* GS  = L;                                     // alias QS+KS: gate tile 64x256
  short* YT  = L + 32768;                             // alias STS: y tile 64x264 (padded)
  const int tid = threadIdx.x, wave = tid >> 6, lane = tid & 63;
  const int n = blockIdx.x, h = blockIdx.y, b = blockIdx.z;
  const size_t rowbase = (size_t)(b * T_LEN + n * 64);
  // ---- stage q(4), k(4), [ST(16)], v(8); issue order matters for counted vmcnt
  {
    int row = wave * 4 + (lane >> 4), sc16 = lane & 15;
    #pragma unroll
    for (int c = 0; c < 4; ++c){
      int r = c * 16 + row, gc = sc16 ^ (r & 7);
      GLOAD16(q + (rowbase + r) * 1024 + h * 128 + gc * 8, &QS[c * 2048 + wave * 512]);
    }
    #pragma unroll
    for (int c = 0; c < 4; ++c){
      int r = c * 16 + row, gc = sc16 ^ (r & 7);
      GLOAD16(k + (rowbase + r) * 1024 + h * 128 + gc * 8, &KS[c * 2048 + wave * 512]);
    }
    __builtin_amdgcn_sched_barrier(0);
    if (n){
      size_t stb = (((size_t)n * 4 + b) * 8 + h) * 32768;
      #pragma unroll
      for (int c = 0; c < 16; ++c){
        int r = c * 16 + row, gc = sc16 ^ (r & 7);
        GLOAD16(ST + stb + (size_t)r * 128 + gc * 8, &STS[c * 2048 + wave * 512]);
      }
    }
    __builtin_amdgcn_sched_barrier(0);
    int row8 = wave * 8 + (lane >> 3), sc8 = lane & 7;
    #pragma unroll
    for (int c = 0; c < 8; ++c){
      int r = c * 32 + row8, gc = sc8 ^ (r & 7);
      GLOAD16(vT + (size_t)(h * 256 + r) * MROWS + rowbase + gc * 8, &VS[c * 2048 + wave * 512]);
    }
  }
  if (n) asm volatile("s_waitcnt vmcnt(24)" ::: "memory");   // q,k done; ST+v in flight
  else   asm volatile("s_waitcnt vmcnt(8)"  ::: "memory");   // q,k done; v in flight
  __builtin_amdgcn_s_barrier();
  __builtin_amdgcn_sched_barrier(0);
  const float lg = log2f(1.0f - exp2f(-(float)(5 + h)));
  // ---- P^T = k q'^T : D[j][i]; wave owns j in [16w,16w+16)
  f32x4 accP[4] = {};
  #pragma unroll
  for (int ks = 0; ks < 4; ++ks){
    int rowA = wave * 16 + (lane & 15);
    int chA = (ks * 4 + (lane >> 4)) ^ (rowA & 7);
    s16x8 af = *(const s16x8*)&KS[rowA * 128 + chA * 8];
    #pragma unroll
    for (int nf = 0; nf < 4; ++nf){
      int rowB = nf * 16 + (lane & 15);
      int chB = (ks * 4 + (lane >> 4)) ^ (rowB & 7);
      s16x8 bfr = *(const s16x8*)&QS[rowB * 128 + chB * 8];
      accP[nf] = __builtin_amdgcn_mfma_f32_16x16x32_bf16(af, bfr, accP[nf], 0, 0, 0);
    }
  }
  {
    int jb = wave * 16 + 4 * (lane >> 4);
    float dj[4];
    #pragma unroll
    for (int r = 0; r < 4; ++r) dj[r] = exp2f(-(float)(jb + r + 1) * lg);
    #pragma unroll
    for (int nf = 0; nf < 4; ++nf){
      int i = nf * 16 + (lane & 15);
      s16x4 pk;
      #pragma unroll
      for (int r = 0; r < 4; ++r)
        pk[r] = f2bf((i >= jb + r) ? accP[nf][r] * dj[r] : 0.0f);
      *(s16x4*)&PS[i * 72 + jb] = pk;
    }
  }
  // ---- o_inter: acc = q'.S ; wave owns e in [64w, 64w+64)
  f32x4 acc[4][4] = {};
  if (n){
    asm volatile("s_waitcnt vmcnt(8)" ::: "memory");         // ST done; v still in flight
    __builtin_amdgcn_s_barrier();
    __builtin_amdgcn_sched_barrier(0);
    #pragma unroll
    for (int ks = 0; ks < 4; ++ks){
      s16x8 af[4];
      #pragma unroll
      for (int mf = 0; mf < 4; ++mf){
        int rowA = mf * 16 + (lane & 15);
        int chA = (ks * 4 + (lane >> 4)) ^ (rowA & 7);
        af[mf] = *(const s16x8*)&QS[rowA * 128 + chA * 8];
      }
      #pragma unroll
      for (int nf = 0; nf < 4; ++nf){
        int e = wave * 64 + nf * 16 + (lane & 15);
        int chB = (ks * 4 + (lane >> 4)) ^ (e & 7);
        s16x8 bfr = *(const s16x8*)&STS[e * 128 + chB * 8];
        #pragma unroll
        for (int mf = 0; mf < 4; ++mf)
          acc[mf][nf] = __builtin_amdgcn_mfma_f32_16x16x32_bf16(af[mf], bfr, acc[mf][nf], 0, 0, 0);
      }
    }
  }
  __syncthreads();            // drain all: v ready, PS visible, QS/KS/STS now dead
  // ---- issue gate staging (into QS/KS region)
  {
    int row = wave * 2 + (lane >> 5), sc32 = lane & 31;
    #pragma unroll
    for (int c = 0; c < 8; ++c){
      int r = c * 8 + row;
      GLOAD16(g + (rowbase + r) * 2048 + h * 256 + sc32 * 8, &GS[c * 2048 + wave * 512]);
    }
  }
  // ---- o_intra: acc += P v
  #pragma unroll
  for (int ks = 0; ks < 2; ++ks){
    s16x8 af[4];
    #pragma unroll
    for (int mf = 0; mf < 4; ++mf){
      int i = mf * 16 + (lane & 15);
      af[mf] = *(const s16x8*)&PS[i * 72 + ks * 32 + (lane >> 4) * 8];
    }
    #pragma unroll
    for (int nf = 0; nf < 4; ++nf){
      int e = wave * 64 + nf * 16 + (lane & 15);
      int ch = (ks * 4 + (lane >> 4)) ^ (e & 7);
      s16x8 bfr = *(const s16x8*)&VS[e * 64 + ch * 8];
      #pragma unroll
      for (int mf = 0; mf < 4; ++mf)
        acc[mf][nf] = __builtin_amdgcn_mfma_f32_16x16x32_bf16(af[mf], bfr, acc[mf][nf], 0, 0, 0);
    }
  }
  // ---- row-wise sum of squares (over e=256): intra-wave shuffle + cross-wave LDS
  float ssp[4][4];
  #pragma unroll
  for (int mf = 0; mf < 4; ++mf)
    #pragma unroll
    for (int r = 0; r < 4; ++r){
      float s = 0.f;
      #pragma unroll
      for (int nf = 0; nf < 4; ++nf) s += acc[mf][nf][r] * acc[mf][nf][r];
      #pragma unroll
      for (int off = 8; off >= 1; off >>= 1) s += __shfl_xor(s, off, 64);
      ssp[mf][r] = s;
    }
  if ((lane & 15) == 0){
    #pragma unroll
    for (int mf = 0; mf < 4; ++mf)
      #pragma unroll
      for (int r = 0; r < 4; ++r){
        int row = mf * 16 + 4 * (lane >> 4) + r;
        SS[row * 4 + wave] = ssp[mf][r];
      }
  }
  __syncthreads();            // SS visible; gate loads drained
  // ---- normalize + gate, write padded y tile
  #pragma unroll
  for (int mf = 0; mf < 4; ++mf){
    float rr[4];
    #pragma unroll
    for (int r = 0; r < 4; ++r){
      int row = mf * 16 + 4 * (lane >> 4) + r;
      f32x4 s4 = *(const f32x4*)&SS[row * 4];
      float tot = s4[0] + s4[1] + s4[2] + s4[3];
      rr[r] = 1.0f / sqrtf(tot * (1.0f / 256.0f) + 1e-5f);
    }
    #pragma unroll
    for (int nf = 0; nf < 4; ++nf){
      int e = wave * 64 + nf * 16 + (lane & 15);
      float nwe = nw[e];
      #pragma unroll
      for (int r = 0; r < 4; ++r){
        int row = mf * 16 + 4 * (lane >> 4) + r;
        float gf = bf2f(GS[row * 256 + e]);
        float sig = 1.0f / (1.0f + expf(-gf));
        YT[row * 264 + e] = f2bf(acc[mf][nf][r] * rr[r] * nwe * gf * sig);
      }
    }
  }
  __syncthreads();
  // ---- coalesced copy out
  #pragma unroll
  for (int it = 0; it < 8; ++it){
    int flat = it * 2048 + tid * 8;
    int row = flat >> 8, e = flat & 255;
    s16x8 v = *(const s16x8*)&YT[row * 264 + e];
    *(s16x8*)&y[(rowbase + row) * 2048 + h * 256 + e] = v;
  }
}

// ---------------- host ----------------
extern "C" void kernel_launch(void* const* d_in, const int* in_sizes, int n_in,
                              void* d_out, int out_size, void* d_ws, size_t ws_size,
                              hipStream_t stream){
  const float* x  = (const float*)d_in[0];
  const float* Wq = (const float*)d_in[1];
  const float* Wk = (const float*)d_in[2];
  const float* Wv = (const float*)d_in[3];
  const float* Wg = (const float*)d_in[4];
  const float* Wo = (const float*)d_in[5];
  const float* nw = (const float*)d_in[6];
  float* out = (float*)d_out;

  // workspace layout (208 MiB total, same as before).
  // yb aliases [0, 32MB) = xb + WT + head of kTt — all dead before ret_fused writes it.
  char* w = (char*)d_ws;
  short* xb  = (short*)w;               w += (size_t)8192 * 1024 * 2;   // 16 MB
  short* WT  = (short*)w;               w += (size_t)6144 * 1024 * 2;   // 12.6 MB (WqT|WkT|WvT|WgT)
  short* kTt = (short*)w;               w += (size_t)1024 * 8192 * 2;   // 16 MB (dead after ret_scan)
  short* qb  = (short*)w;               w += (size_t)8192 * 1024 * 2;   // 16 MB
  short* kb  = (short*)w;               w += (size_t)8192 * 1024 * 2;   // 16 MB
  short* vT  = (short*)w;               w += (size_t)2048 * 8192 * 2;   // 32 MB
  short* gb  = (short*)w;               w += (size_t)8192 * 2048 * 2;   // 32 MB
  short* STb = (short*)w;               w += (size_t)32 * 4 * 8 * 32768 * 2; // 64 MB
  short* WoT = (short*)w;               w += (size_t)1024 * 2048 * 2;   // 4 MB
  short* yb  = (short*)d_ws;                                            // alias, 32 MB

  cvt_f32_bf16<<<8192, 256, 0, stream>>>(x, xb, 8192 * 1024 / 4);
  dim3 tb(32, 8);
  tr_w<<<dim3(32, 32), tb, 0, stream>>>(Wq, WT,                       1024, 1024);
  tr_w<<<dim3(32, 32), tb, 0, stream>>>(Wk, WT + (size_t)1024 * 1024, 1024, 1024);
  tr_w<<<dim3(64, 32), tb, 0, stream>>>(Wv, WT + (size_t)2048 * 1024, 1024, 2048);
  tr_w<<<dim3(64, 32), tb, 0, stream>>>(Wg, WT + (size_t)4096 * 1024, 1024, 2048);
  tr_w<<<dim3(32, 64), tb, 0, stream>>>(Wo, WoT,                      2048, 1024);

  gemm_bt<0><<<dim3(64,  8), 256, 0, stream>>>(xb, WT,                       qb, 1024, 1024);
  gemm_bt<0><<<dim3(64,  8), 256, 0, stream>>>(xb, WT + (size_t)1024 * 1024, kb, 1024, 1024);
  gemm_bt<1><<<dim3(64, 16), 256, 0, stream>>>(xb, WT + (size_t)2048 * 1024, vT, 1024, 2048);
  gemm_bt<0><<<dim3(64, 16), 256, 0, stream>>>(xb, WT + (size_t)4096 * 1024, gb, 1024, 2048);

  rope_inplace<<<16384, 256, 0, stream>>>(qb, 0.08838834764831845f, 1);  // DK^-0.5 + dec_q bake
  rope_inplace<<<16384, 256, 0, stream>>>(kb, 1.0f, 0);
  tr_k_decay<<<dim3(32, 256), tb, 0, stream>>>(kb, kTt);

  ret_scan <<<dim3(8, 8, 4),  256, 0, stream>>>(kTt, vT, STb);
  ret_fused<<<dim3(32, 8, 4), 256, 0, stream>>>(qb, kb, vT, STb, gb, nw, yb);
  gemm_bt<2><<<dim3(64, 8), 256, 0, stream>>>(yb, WoT, out, 2048, 1024);
}

// Round 3
// 323.139 us; speedup vs baseline: 1.0987x; 1.0711x over previous
//
#include <hip/hip_runtime.h>
#include <hip/hip_bf16.h>
#include <cstdint>
#include <cstddef>

using f32x4 = __attribute__((ext_vector_type(4))) float;
using s16x8 = __attribute__((ext_vector_type(8))) short;
using s16x4 = __attribute__((ext_vector_type(4))) short;

#define DEVINL __device__ __forceinline__

static constexpr int T_LEN  = 2048;
static constexpr int MROWS  = 8192;   // B*T
static constexpr int NCHUNK = 32;     // T / 64

DEVINL float bf2f(short s){
  unsigned u = ((unsigned)(unsigned short)s) << 16;
  return __builtin_bit_cast(float, u);
}
DEVINL short f2bf(float f){
  unsigned u = __builtin_bit_cast(unsigned, f);
  u = (u + 0x7fffu + ((u >> 16) & 1u)) >> 16;
  return (short)(unsigned short)u;
}

// async global->LDS, 16B per lane; LDS dest must be wave-uniform base (+lane*16 implicit)
#define GLOAD16(gp, lp) \
  __builtin_amdgcn_global_load_lds((__attribute__((address_space(1))) void*)(gp), \
                                   (__attribute__((address_space(3))) void*)(lp), 16, 0, 0)

#define MFMA16(a, b, c) __builtin_amdgcn_mfma_f32_16x16x32_bf16((a), (b), (c), 0, 0, 0)

// ---------------- elementwise f32 -> bf16 ----------------
__global__ __launch_bounds__(256) void cvt_f32_bf16(const float* __restrict__ in,
                                                    short* __restrict__ out, int n4){
  int i = blockIdx.x * 256 + threadIdx.x;
  if (i >= n4) return;
  float4 v = ((const float4*)in)[i];
  short4 o;
  o.x = f2bf(v.x); o.y = f2bf(v.y); o.z = f2bf(v.z); o.w = f2bf(v.w);
  ((short4*)out)[i] = o;
}

// ---------------- transpose f32 [R][C] -> bf16 [C][R] ----------------
__global__ __launch_bounds__(256) void tr_w(const float* __restrict__ in,
                                            short* __restrict__ out, int R, int C){
  __shared__ float tile[32][33];
  int c0 = blockIdx.x * 32, r0 = blockIdx.y * 32;
  int tx = threadIdx.x, ty = threadIdx.y;           // (32,8)
  #pragma unroll
  for (int i = 0; i < 4; ++i){
    int r = ty + i * 8;
    tile[r][tx] = in[(size_t)(r0 + r) * C + c0 + tx];
  }
  __syncthreads();
  #pragma unroll
  for (int i = 0; i < 4; ++i){
    int c = ty + i * 8;
    out[(size_t)(c0 + c) * R + r0 + tx] = f2bf(tile[tx][c]);
  }
}

// ------- transpose bf16 k [8192][1024] -> kT [1024][8192], baking dec_k = gamma^(63-j) -------
__global__ __launch_bounds__(256) void tr_k_decay(const short* __restrict__ in,
                                                  short* __restrict__ out){
  __shared__ float tile[32][33];
  int c0 = blockIdx.x * 32, r0 = blockIdx.y * 32;   // c over 1024 feature cols, r over 8192 rows
  int tx = threadIdx.x, ty = threadIdx.y;
  #pragma unroll
  for (int i = 0; i < 4; ++i){
    int r = ty + i * 8;
    tile[r][tx] = bf2f(in[(size_t)(r0 + r) * 1024 + c0 + tx]);
  }
  __syncthreads();
  #pragma unroll
  for (int i = 0; i < 4; ++i){
    int c  = c0 + ty + i * 8;
    int h  = c >> 7;
    float lg = log2f(1.0f - exp2f(-(float)(5 + h)));
    int srow = r0 + tx;
    int j = srow & 63;
    float dec = exp2f((float)(63 - j) * lg);
    out[(size_t)c * MROWS + srow] = f2bf(tile[tx][ty + i * 8] * dec);
  }
}

// ---------------- rope cos/sin table [2048][64] float2 ----------------
__global__ __launch_bounds__(256) void rope_table(float* __restrict__ tab){
  int i = blockIdx.x * 256 + threadIdx.x;           // t*64+d, 131072 total
  int t = i >> 6, d = i & 63;
  float inv = exp2f(-(float)d * (13.287712379549449f / 64.0f));  // 10000^(-d/64)
  float f = (float)t * inv;
  float s, c;
  sincosf(f, &s, &c);
  tab[2 * i]     = c;
  tab[2 * i + 1] = s;
}

// ------- RoPE in-place on bf16 [8192][1024]; optional dec_q = gamma^((t%64)+1) bake (q only) -------
__global__ __launch_bounds__(256) void rope_inplace(short* __restrict__ qk,
                                                    const float* __restrict__ tab,
                                                    float scale, int bake){
  int idx = blockIdx.x * 256 + threadIdx.x;         // 8192 * 512 threads
  int bt  = idx >> 9, rem = idx & 511;
  int h   = rem >> 6, d = rem & 63;
  int t   = bt & (T_LEN - 1);
  float2 cs = ((const float2*)tab)[t * 64 + d];
  float mult = scale;
  if (bake){
    float lg = log2f(1.0f - exp2f(-(float)(5 + h)));
    mult *= exp2f((float)((t & 63) + 1) * lg);      // gamma^(i+1)
  }
  size_t base = (size_t)bt * 1024 + h * 128 + d;
  float x1 = bf2f(qk[base]), x2 = bf2f(qk[base + 64]);
  qk[base]      = f2bf((x1 * cs.x - x2 * cs.y) * mult);
  qk[base + 64] = f2bf((x2 * cs.x + x1 * cs.y) * mult);
}

// ---------------- 128x128x(BK=64) bt-GEMM: C[m][n] = sum_k A[m][k]*Bt[n][k] ----------------
// MODE 0: bf16 row-major out [M][N]; MODE 1: bf16 transposed out [N][MROWS]; MODE 2: f32 out [M][N]
template<int MODE>
__global__ __launch_bounds__(256) void gemm_bt(const short* __restrict__ A,
                                               const short* __restrict__ Bt,
                                               void* __restrict__ out, int K, int N){
  __shared__ alignas(16) short As[128 * 64];
  __shared__ alignas(16) short Bs[128 * 64];
  const int tid = threadIdx.x, wave = tid >> 6, lane = tid & 63;
  const int m0 = blockIdx.x * 128, n0 = blockIdx.y * 128;
  const int wm = (wave & 1) * 64, wn = (wave >> 1) * 64;
  f32x4 acc[4][4] = {};
  const int srow = wave * 8 + (lane >> 3);          // staging row-in-call (rows are 128B)
  const int sc   = lane & 7;                        // staging 16B-chunk within row
  const int kT = K >> 6;
  for (int kt = 0; kt < kT; ++kt){
    const int k0 = kt << 6;
    #pragma unroll
    for (int c = 0; c < 4; ++c){
      int row = c * 32 + srow;
      int gc  = sc ^ (row & 7);                     // pre-swizzled global source
      GLOAD16(A  + (size_t)(m0 + row) * K + k0 + gc * 8, &As[c * 2048 + wave * 512]);
      GLOAD16(Bt + (size_t)(n0 + row) * K + k0 + gc * 8, &Bs[c * 2048 + wave * 512]);
    }
    __syncthreads();
    #pragma unroll
    for (int ks = 0; ks < 2; ++ks){
      s16x8 af[4], bfr[4];
      #pragma unroll
      for (int mf = 0; mf < 4; ++mf){
        int row = wm + mf * 16 + (lane & 15);
        int ch  = (ks * 4 + (lane >> 4)) ^ (row & 7);
        af[mf] = *(const s16x8*)&As[row * 64 + ch * 8];
      }
      #pragma unroll
      for (int nf = 0; nf < 4; ++nf){
        int row = wn + nf * 16 + (lane & 15);
        int ch  = (ks * 4 + (lane >> 4)) ^ (row & 7);
        bfr[nf] = *(const s16x8*)&Bs[row * 64 + ch * 8];
      }
      #pragma unroll
      for (int mf = 0; mf < 4; ++mf)
        #pragma unroll
        for (int nf = 0; nf < 4; ++nf)
          acc[mf][nf] = MFMA16(af[mf], bfr[nf], acc[mf][nf]);
    }
    __syncthreads();
  }
  #pragma unroll
  for (int mf = 0; mf < 4; ++mf){
    #pragma unroll
    for (int nf = 0; nf < 4; ++nf){
      int col   = n0 + wn + nf * 16 + (lane & 15);
      int rbase = m0 + wm + mf * 16 + 4 * (lane >> 4);
      f32x4 v = acc[mf][nf];
      if (MODE == 0){
        short* o = (short*)out;
        #pragma unroll
        for (int r = 0; r < 4; ++r) o[(size_t)(rbase + r) * N + col] = f2bf(v[r]);
      } else if (MODE == 1){
        short* o = (short*)out;
        s16x4 pk; pk[0] = f2bf(v[0]); pk[1] = f2bf(v[1]); pk[2] = f2bf(v[2]); pk[3] = f2bf(v[3]);
        *(s16x4*)&o[(size_t)col * MROWS + rbase] = pk;
      } else {
        float* o = (float*)out;
        #pragma unroll
        for (int r = 0; r < 4; ++r) o[(size_t)(rbase + r) * N + col] = v[r];
      }
    }
  }
}

// ---------------- retention state scan: S in MFMA accumulators, write bf16 ST[n] snapshots ----------------
// grid (8=db*eb, 8, 4); 256 thr. Block owns d-range 64 (db) x e-range 64 (eb).
// Triple-buffered LDS, 2-deep prefetch, counted vmcnt (loads stay in flight across barriers).
__global__ __launch_bounds__(256) void ret_scan(const short* __restrict__ kT,
                                                const short* __restrict__ vT,
                                                short* __restrict__ ST){
  __shared__ alignas(16) short kbuf[3][4096];
  __shared__ alignas(16) short vbuf[3][4096];
  const int tid = threadIdx.x, wave = tid >> 6, lane = tid & 63;
  const int db = blockIdx.x & 1, eb = blockIdx.x >> 1;
  const int h = blockIdx.y, b = blockIdx.z;
  const int d0 = db * 64, e0 = eb * 64;
  const float lg = log2f(1.0f - exp2f(-(float)(5 + h)));
  const float gC = exp2f(64.0f * lg);
  f32x4 Sacc[4] = {};
  const int srow = wave * 8 + (lane >> 3);
  const int sc   = lane & 7;

  auto STAGE = [&](int n, int buf){
    size_t rowbase = (size_t)(b * T_LEN + n * 64);
    #pragma unroll
    for (int c = 0; c < 2; ++c){
      int r = c * 32 + srow;
      int gc = sc ^ (r & 7);
      GLOAD16(kT + (size_t)(h * 128 + d0 + r) * MROWS + rowbase + gc * 8,
              &kbuf[buf][c * 2048 + wave * 512]);
    }
    #pragma unroll
    for (int c = 0; c < 2; ++c){
      int r = c * 32 + srow;
      int gc = sc ^ (r & 7);
      GLOAD16(vT + (size_t)(h * 256 + e0 + r) * MROWS + rowbase + gc * 8,
              &vbuf[buf][c * 2048 + wave * 512]);
    }
  };

  STAGE(0, 0);
  STAGE(1, 1);
  for (int n = 0; n < NCHUNK; ++n){
    const int buf = n % 3;
    if (n + 2 < NCHUNK) STAGE(n + 2, (n + 2) % 3);      // 4 loads
    if (n > 0){                                          // 4 stores (snapshot BEFORE this chunk)
      size_t stb = (((size_t)n * 4 + b) * 8 + h) * 32768;
      int dbase = d0 + 16 * wave + 4 * (lane >> 4);
      #pragma unroll
      for (int nf = 0; nf < 4; ++nf){
        int e = e0 + nf * 16 + (lane & 15);
        s16x4 pk;
        #pragma unroll
        for (int r = 0; r < 4; ++r) pk[r] = f2bf(Sacc[nf][r]);
        *(s16x4*)&ST[stb + (size_t)e * 128 + dbase] = pk;
      }
    }
    // counted vmcnt: guarantee chunk-n loads complete; newer loads/stores stay outstanding
    if (n == 0)       asm volatile("s_waitcnt vmcnt(8)"  ::: "memory");
    else if (n < 30)  asm volatile("s_waitcnt vmcnt(12)" ::: "memory");
    else if (n == 30) asm volatile("s_waitcnt vmcnt(8)"  ::: "memory");
    else              asm volatile("s_waitcnt vmcnt(4)"  ::: "memory");
    __builtin_amdgcn_s_barrier();
    __builtin_amdgcn_sched_barrier(0);
    #pragma unroll
    for (int nf = 0; nf < 4; ++nf)
      #pragma unroll
      for (int r = 0; r < 4; ++r) Sacc[nf][r] *= gC;
    #pragma unroll
    for (int ks = 0; ks < 2; ++ks){
      int d = 16 * wave + (lane & 15);
      int chA = (ks * 4 + (lane >> 4)) ^ (d & 7);
      s16x8 af = *(const s16x8*)&kbuf[buf][d * 64 + chA * 8];
      #pragma unroll
      for (int nf = 0; nf < 4; ++nf){
        int e = nf * 16 + (lane & 15);
        int chB = (ks * 4 + (lane >> 4)) ^ (e & 7);
        s16x8 bv = *(const s16x8*)&vbuf[buf][e * 64 + chB * 8];
        Sacc[nf] = MFMA16(af, bv, Sacc[nf]);
      }
    }
    __builtin_amdgcn_s_barrier();
    __builtin_amdgcn_sched_barrier(0);
  }
}

// ---------------- fused per-chunk retention + RMS-norm + SiLU gate (reg-direct) ----------------
// grid (n=32, h=8, b=4); 256 thr; 2 blocks/CU. o = q'.S_n + (mask.*q'k^T).v ; y = o/rms*nw*g*sig(g)
// All MFMA operands except P are loaded global->register directly (fragment-contiguous layouts).
__global__ __launch_bounds__(256, 2) void ret_fused(const short* __restrict__ q,
                                                    const short* __restrict__ k,
                                                    const short* __restrict__ vT,
                                                    const short* __restrict__ ST,
                                                    const short* __restrict__ g,
                                                    const float* __restrict__ nw,
                                                    short* __restrict__ y){
  __shared__ alignas(16) short GS[16384];             // gate tile [64][256]
  __shared__ alignas(16) float SS[256];               // cross-wave sum-of-squares
  __shared__ alignas(16) short XS[16896];             // phase1: PS [64][72]; phase2: YT [64][264]
  short* PS = XS;
  short* YT = XS;
  const int tid = threadIdx.x, wave = tid >> 6, lane = tid & 63;
  const int l15 = lane & 15, lhi = lane >> 4;
  const int n = blockIdx.x, h = blockIdx.y, b = blockIdx.z;
  const size_t rowbase = (size_t)(b * T_LEN + n * 64);
  // ---- issue gate staging first (consumed in epilogue; drained by syncthreads)
  {
    int row = wave * 2 + (lane >> 5), sc32 = lane & 31;
    #pragma unroll
    for (int c = 0; c < 8; ++c){
      int r = c * 8 + row;
      GLOAD16(g + (rowbase + r) * 2048 + h * 256 + sc32 * 8, &GS[c * 2048 + wave * 512]);
    }
  }
  // ---- Q fragments (reused as P-phase B-operand AND o_inter A-operand)
  s16x8 Qf[4][4];
  #pragma unroll
  for (int rf = 0; rf < 4; ++rf)
    #pragma unroll
    for (int ks = 0; ks < 4; ++ks)
      Qf[rf][ks] = *(const s16x8*)&q[(rowbase + rf * 16 + l15) * 1024 + h * 128 + ks * 32 + lhi * 8];
  // ---- K fragments (P-phase A-operand; wave-specific j rows)
  s16x8 Kf[4];
  #pragma unroll
  for (int ks = 0; ks < 4; ++ks)
    Kf[ks] = *(const s16x8*)&k[(rowbase + wave * 16 + l15) * 1024 + h * 128 + ks * 32 + lhi * 8];
  // ---- P^T = k q'^T : D[j][i]; wave owns j in [16w,16w+16)
  f32x4 accP[4] = {};
  #pragma unroll
  for (int ks = 0; ks < 4; ++ks)
    #pragma unroll
    for (int nf = 0; nf < 4; ++nf)
      accP[nf] = MFMA16(Kf[ks], Qf[nf][ks], accP[nf]);
  const float lg = log2f(1.0f - exp2f(-(float)(5 + h)));
  {
    int jb = wave * 16 + 4 * lhi;
    float dj[4];
    #pragma unroll
    for (int r = 0; r < 4; ++r) dj[r] = exp2f(-(float)(jb + r + 1) * lg);
    #pragma unroll
    for (int nf = 0; nf < 4; ++nf){
      int i = nf * 16 + l15;
      s16x4 pk;
      #pragma unroll
      for (int r = 0; r < 4; ++r)
        pk[r] = f2bf((i >= jb + r) ? accP[nf][r] * dj[r] : 0.0f);
      *(s16x4*)&PS[i * 72 + jb] = pk;
    }
  }
  // ---- o_inter: acc = q'.S (ST fragments streamed global->reg); wave owns e in [64w,64w+64)
  f32x4 acc[4][4] = {};
  if (n){
    size_t stb = (((size_t)n * 4 + b) * 8 + h) * 32768;
    #pragma unroll
    for (int ks = 0; ks < 4; ++ks){
      s16x8 Sf[4];
      #pragma unroll
      for (int nf = 0; nf < 4; ++nf){
        int e = wave * 64 + nf * 16 + l15;
        Sf[nf] = *(const s16x8*)&ST[stb + (size_t)e * 128 + ks * 32 + lhi * 8];
      }
      #pragma unroll
      for (int mf = 0; mf < 4; ++mf)
        #pragma unroll
        for (int nf = 0; nf < 4; ++nf)
          acc[mf][nf] = MFMA16(Qf[mf][ks], Sf[nf], acc[mf][nf]);
    }
  }
  // ---- hoist V fragment loads above the PS barrier (latency hides under barrier wait)
  s16x8 Vf[2][4];
  #pragma unroll
  for (int ks2 = 0; ks2 < 2; ++ks2)
    #pragma unroll
    for (int nf = 0; nf < 4; ++nf){
      int e = wave * 64 + nf * 16 + l15;
      Vf[ks2][nf] = *(const s16x8*)&vT[(size_t)(h * 256 + e) * MROWS + rowbase + ks2 * 32 + lhi * 8];
    }
  __syncthreads();                                   // PS visible (also drains GS staging)
  // ---- o_intra: acc += P v  (P from LDS, V from regs)
  #pragma unroll
  for (int ks2 = 0; ks2 < 2; ++ks2){
    s16x8 Pf[4];
    #pragma unroll
    for (int mf = 0; mf < 4; ++mf)
      Pf[mf] = *(const s16x8*)&PS[(mf * 16 + l15) * 72 + ks2 * 32 + lhi * 8];
    #pragma unroll
    for (int mf = 0; mf < 4; ++mf)
      #pragma unroll
      for (int nf = 0; nf < 4; ++nf)
        acc[mf][nf] = MFMA16(Pf[mf], Vf[ks2][nf], acc[mf][nf]);
  }
  // ---- row-wise sum of squares (over e=256): intra-wave shuffle + cross-wave LDS
  float ssp[4][4];
  #pragma unroll
  for (int mf = 0; mf < 4; ++mf)
    #pragma unroll
    for (int r = 0; r < 4; ++r){
      float s = 0.f;
      #pragma unroll
      for (int nf = 0; nf < 4; ++nf) s += acc[mf][nf][r] * acc[mf][nf][r];
      #pragma unroll
      for (int off = 8; off >= 1; off >>= 1) s += __shfl_xor(s, off, 64);
      ssp[mf][r] = s;
    }
  if (l15 == 0){
    #pragma unroll
    for (int mf = 0; mf < 4; ++mf)
      #pragma unroll
      for (int r = 0; r < 4; ++r){
        int row = mf * 16 + 4 * lhi + r;
        SS[row * 4 + wave] = ssp[mf][r];
      }
  }
  __syncthreads();                                   // SS + GS ready; PS dead (YT aliases it)
  // ---- normalize + gate, write padded y tile
  #pragma unroll
  for (int mf = 0; mf < 4; ++mf){
    float rr[4];
    #pragma unroll
    for (int r = 0; r < 4; ++r){
      int row = mf * 16 + 4 * lhi + r;
      f32x4 s4 = *(const f32x4*)&SS[row * 4];
      float tot = s4[0] + s4[1] + s4[2] + s4[3];
      rr[r] = __builtin_amdgcn_rsqf(tot * (1.0f / 256.0f) + 1e-5f);
    }
    #pragma unroll
    for (int nf = 0; nf < 4; ++nf){
      int e = wave * 64 + nf * 16 + l15;
      float nwe = nw[e];
      #pragma unroll
      for (int r = 0; r < 4; ++r){
        int row = mf * 16 + 4 * lhi + r;
        float gf = bf2f(GS[row * 256 + e]);
        float sig = __builtin_amdgcn_rcpf(1.0f + exp2f(gf * -1.4426950408889634f));
        YT[row * 264 + e] = f2bf(acc[mf][nf][r] * rr[r] * nwe * gf * sig);
      }
    }
  }
  __syncthreads();
  // ---- coalesced copy out
  #pragma unroll
  for (int it = 0; it < 8; ++it){
    int flat = it * 2048 + tid * 8;
    int row = flat >> 8, e = flat & 255;
    s16x8 v = *(const s16x8*)&YT[row * 264 + e];
    *(s16x8*)&y[(rowbase + row) * 2048 + h * 256 + e] = v;
  }
}

// ---------------- host ----------------
extern "C" void kernel_launch(void* const* d_in, const int* in_sizes, int n_in,
                              void* d_out, int out_size, void* d_ws, size_t ws_size,
                              hipStream_t stream){
  const float* x  = (const float*)d_in[0];
  const float* Wq = (const float*)d_in[1];
  const float* Wk = (const float*)d_in[2];
  const float* Wv = (const float*)d_in[3];
  const float* Wg = (const float*)d_in[4];
  const float* Wo = (const float*)d_in[5];
  const float* nw = (const float*)d_in[6];
  float* out = (float*)d_out;

  // workspace layout (208 MiB total).
  // yb aliases [0, 32MB) = xb + WT + head of kTt — all dead before ret_fused writes it.
  // rope table aliases STb's n=0 slice (first 2MB; scan only writes n>=1, fused only reads n>=1).
  char* w = (char*)d_ws;
  short* xb  = (short*)w;               w += (size_t)8192 * 1024 * 2;   // 16 MB
  short* WT  = (short*)w;               w += (size_t)6144 * 1024 * 2;   // 12.6 MB (WqT|WkT|WvT|WgT)
  short* kTt = (short*)w;               w += (size_t)1024 * 8192 * 2;   // 16 MB (dead after ret_scan)
  short* qb  = (short*)w;               w += (size_t)8192 * 1024 * 2;   // 16 MB
  short* kb  = (short*)w;               w += (size_t)8192 * 1024 * 2;   // 16 MB
  short* vT  = (short*)w;               w += (size_t)2048 * 8192 * 2;   // 32 MB
  short* gb  = (short*)w;               w += (size_t)8192 * 2048 * 2;   // 32 MB
  short* STb = (short*)w;               w += (size_t)32 * 4 * 8 * 32768 * 2; // 64 MB
  short* WoT = (short*)w;               w += (size_t)1024 * 2048 * 2;   // 4 MB
  short* yb  = (short*)d_ws;                                            // alias, 32 MB
  float* tab = (float*)STb;                                             // alias, 1 MB (n=0 slice)

  cvt_f32_bf16<<<8192, 256, 0, stream>>>(x, xb, 8192 * 1024 / 4);
  dim3 tb(32, 8);
  tr_w<<<dim3(32, 32), tb, 0, stream>>>(Wq, WT,                       1024, 1024);
  tr_w<<<dim3(32, 32), tb, 0, stream>>>(Wk, WT + (size_t)1024 * 1024, 1024, 1024);
  tr_w<<<dim3(64, 32), tb, 0, stream>>>(Wv, WT + (size_t)2048 * 1024, 1024, 2048);
  tr_w<<<dim3(64, 32), tb, 0, stream>>>(Wg, WT + (size_t)4096 * 1024, 1024, 2048);
  tr_w<<<dim3(32, 64), tb, 0, stream>>>(Wo, WoT,                      2048, 1024);
  rope_table<<<512, 256, 0, stream>>>(tab);

  gemm_bt<0><<<dim3(64,  8), 256, 0, stream>>>(xb, WT,                       qb, 1024, 1024);
  gemm_bt<0><<<dim3(64,  8), 256, 0, stream>>>(xb, WT + (size_t)1024 * 1024, kb, 1024, 1024);
  gemm_bt<1><<<dim3(64, 16), 256, 0, stream>>>(xb, WT + (size_t)2048 * 1024, vT, 1024, 2048);
  gemm_bt<0><<<dim3(64, 16), 256, 0, stream>>>(xb, WT + (size_t)4096 * 1024, gb, 1024, 2048);

  rope_inplace<<<16384, 256, 0, stream>>>(qb, tab, 0.08838834764831845f, 1);  // DK^-0.5 + dec_q
  rope_inplace<<<16384, 256, 0, stream>>>(kb, tab, 1.0f, 0);
  tr_k_decay<<<dim3(32, 256), tb, 0, stream>>>(kb, kTt);

  ret_scan <<<dim3(8, 8, 4),  256, 0, stream>>>(kTt, vT, STb);
  ret_fused<<<dim3(32, 8, 4), 256, 0, stream>>>(qb, kb, vT, STb, gb, nw, yb);
  gemm_bt<2><<<dim3(64, 8), 256, 0, stream>>>(yb, WoT, out, 2048, 1024);
}

// Round 4
// 307.108 us; speedup vs baseline: 1.1561x; 1.0522x over previous
//
#include <hip/hip_runtime.h>
#include <hip/hip_bf16.h>
#include <cstdint>
#include <cstddef>

using f32x4 = __attribute__((ext_vector_type(4))) float;
using s16x8 = __attribute__((ext_vector_type(8))) short;
using s16x4 = __attribute__((ext_vector_type(4))) short;

#define DEVINL __device__ __forceinline__

static constexpr int T_LEN  = 2048;
static constexpr int MROWS  = 8192;   // B*T
static constexpr int NCHUNK = 32;     // T / 64

DEVINL float bf2f(short s){
  unsigned u = ((unsigned)(unsigned short)s) << 16;
  return __builtin_bit_cast(float, u);
}
DEVINL short f2bf(float f){
  unsigned u = __builtin_bit_cast(unsigned, f);
  u = (u + 0x7fffu + ((u >> 16) & 1u)) >> 16;
  return (short)(unsigned short)u;
}

// async global->LDS, 16B per lane; LDS dest must be wave-uniform base (+lane*16 implicit)
#define GLOAD16(gp, lp) \
  __builtin_amdgcn_global_load_lds((__attribute__((address_space(1))) void*)(gp), \
                                   (__attribute__((address_space(3))) void*)(lp), 16, 0, 0)

#define MFMA16(a, b, c) __builtin_amdgcn_mfma_f32_16x16x32_bf16((a), (b), (c), 0, 0, 0)

// ---------------- elementwise f32 -> bf16 ----------------
__global__ __launch_bounds__(256) void cvt_f32_bf16(const float* __restrict__ in,
                                                    short* __restrict__ out, int n4){
  int i = blockIdx.x * 256 + threadIdx.x;
  if (i >= n4) return;
  float4 v = ((const float4*)in)[i];
  short4 o;
  o.x = f2bf(v.x); o.y = f2bf(v.y); o.z = f2bf(v.z); o.w = f2bf(v.w);
  ((short4*)out)[i] = o;
}

// ---------------- transpose f32 [R][C] -> bf16 [C][R] ----------------
__global__ __launch_bounds__(256) void tr_w(const float* __restrict__ in,
                                            short* __restrict__ out, int R, int C){
  __shared__ float tile[32][33];
  int c0 = blockIdx.x * 32, r0 = blockIdx.y * 32;
  int tx = threadIdx.x, ty = threadIdx.y;           // (32,8)
  #pragma unroll
  for (int i = 0; i < 4; ++i){
    int r = ty + i * 8;
    tile[r][tx] = in[(size_t)(r0 + r) * C + c0 + tx];
  }
  __syncthreads();
  #pragma unroll
  for (int i = 0; i < 4; ++i){
    int c = ty + i * 8;
    out[(size_t)(c0 + c) * R + r0 + tx] = f2bf(tile[tx][c]);
  }
}

// ------- transpose bf16 k [8192][1024] -> kT [1024][8192], baking dec_k = gamma^(63-j) -------
__global__ __launch_bounds__(256) void tr_k_decay(const short* __restrict__ in,
                                                  short* __restrict__ out){
  __shared__ float tile[32][33];
  int c0 = blockIdx.x * 32, r0 = blockIdx.y * 32;   // c over 1024 feature cols, r over 8192 rows
  int tx = threadIdx.x, ty = threadIdx.y;
  #pragma unroll
  for (int i = 0; i < 4; ++i){
    int r = ty + i * 8;
    tile[r][tx] = bf2f(in[(size_t)(r0 + r) * 1024 + c0 + tx]);
  }
  __syncthreads();
  #pragma unroll
  for (int i = 0; i < 4; ++i){
    int c  = c0 + ty + i * 8;
    int h  = c >> 7;
    float lg = log2f(1.0f - exp2f(-(float)(5 + h)));
    int srow = r0 + tx;
    int j = srow & 63;
    float dec = exp2f((float)(63 - j) * lg);
    out[(size_t)c * MROWS + srow] = f2bf(tile[tx][ty + i * 8] * dec);
  }
}

// ---------------- rope cos/sin table [2048][64] float2 ----------------
__global__ __launch_bounds__(256) void rope_table(float* __restrict__ tab){
  int i = blockIdx.x * 256 + threadIdx.x;           // t*64+d, 131072 total
  int t = i >> 6, d = i & 63;
  float inv = exp2f(-(float)d * (13.287712379549449f / 64.0f));  // 10000^(-d/64)
  float f = (float)t * inv;
  float s, c;
  sincosf(f, &s, &c);
  tab[2 * i]     = c;
  tab[2 * i + 1] = s;
}

// ------- RoPE in-place on bf16 [8192][1024]; optional dec_q = gamma^((t%64)+1) bake (q only) -------
__global__ __launch_bounds__(256) void rope_inplace(short* __restrict__ qk,
                                                    const float* __restrict__ tab,
                                                    float scale, int bake){
  int idx = blockIdx.x * 256 + threadIdx.x;         // 8192 * 512 threads
  int bt  = idx >> 9, rem = idx & 511;
  int h   = rem >> 6, d = rem & 63;
  int t   = bt & (T_LEN - 1);
  float2 cs = ((const float2*)tab)[t * 64 + d];
  float mult = scale;
  if (bake){
    float lg = log2f(1.0f - exp2f(-(float)(5 + h)));
    mult *= exp2f((float)((t & 63) + 1) * lg);      // gamma^(i+1)
  }
  size_t base = (size_t)bt * 1024 + h * 128 + d;
  float x1 = bf2f(qk[base]), x2 = bf2f(qk[base + 64]);
  qk[base]      = f2bf((x1 * cs.x - x2 * cs.y) * mult);
  qk[base + 64] = f2bf((x2 * cs.x + x1 * cs.y) * mult);
}

// ======= 256x256 8-phase GEMM (BK=64, 8 waves, double-buffered 128KiB LDS, counted vmcnt) =======
// C[m][n] = sum_k A[m][k] * Bt[n][k].  M fixed = 8192 (32 m-blocks).
// MODE 2: f32 row-major out (N=1024), o0. MODE 3: fused projection epilogue (N=6144):
//   n in [0,1024) -> o0=qb bf16 [8192][1024]; [1024,2048) -> o1=kb; [2048,4096) -> o2=vT
//   transposed [2048][8192]; [4096,6144) -> o3=gb [8192][2048].
DEVINL void stage_half(const short* __restrict__ src, int ldk, int t, int half,
                       short* lbase, int wave, int lane){
  const int sr = lane >> 3;
  const int gc = ((lane & 7) ^ sr) * 8;             // pre-swizzled source chunk
  const size_t k0 = (size_t)t * 64;
  #pragma unroll
  for (int c = 0; c < 2; ++c){
    int r0 = half * 128 + c * 64;
    GLOAD16(src + (size_t)(r0 + wave * 8 + sr) * ldk + k0 + gc,
            lbase + (r0 + wave * 8) * 64);
  }
}

DEVINL s16x8 frag64(const short* buf, int row, int ks, int lhi){
  int ch = (ks * 4 + lhi) ^ (row & 7);
  return *(const s16x8*)&buf[row * 64 + ch * 8];
}

template<int MODE>
__global__ __launch_bounds__(512, 2) void gemm256(const short* __restrict__ A,
                                                  const short* __restrict__ Bt,
                                                  void* __restrict__ o0, void* __restrict__ o1,
                                                  void* __restrict__ o2, void* __restrict__ o3,
                                                  int K, int nt){
  __shared__ alignas(16) short LBUF[65536];         // A[2][256*64] | B[2][256*64]
  const int tid = threadIdx.x, wave = tid >> 6, lane = tid & 63;
  const int l15 = lane & 15, lhi = lane >> 4;
  const int wm = (wave >> 2) * 128, wn = (wave & 3) * 64;
  // XCD-bijective swizzle (gridDim.x divisible by 8)
  const int cpx = gridDim.x >> 3;
  const int swz = (blockIdx.x & 7) * cpx + (blockIdx.x >> 3);
  const int m0 = (swz & 31) * 256, n0 = (swz >> 5) * 256;
  const short* Ag = A + (size_t)m0 * K;
  const short* Bg = Bt + (size_t)n0 * K;
  f32x4 acc[8][4] = {};
  // ---- prologue: tile0 (A0,A1,B0,B1) + tile1 (B0,B1); counted drain to tile0
  stage_half(Ag, K, 0, 0, LBUF,                 wave, lane);
  stage_half(Ag, K, 0, 1, LBUF,                 wave, lane);
  stage_half(Bg, K, 0, 0, LBUF + 32768,         wave, lane);
  stage_half(Bg, K, 0, 1, LBUF + 32768,         wave, lane);
  stage_half(Bg, K, 1, 0, LBUF + 32768 + 16384, wave, lane);
  stage_half(Bg, K, 1, 1, LBUF + 32768 + 16384, wave, lane);
  asm volatile("s_waitcnt vmcnt(4)" ::: "memory");
  __builtin_amdgcn_sched_barrier(0);
  __builtin_amdgcn_s_barrier();
  // ---- main loop: 4 phases per K-tile
  for (int t = 0; t < nt; ++t){
    short* Ab = LBUF + (t & 1) * 16384;
    short* Bb = LBUF + 32768 + (t & 1) * 16384;
    s16x8 bfr[2][4];
    #pragma unroll
    for (int q = 0; q < 4; ++q){
      if (q == 0){
        #pragma unroll
        for (int ks = 0; ks < 2; ++ks)
          #pragma unroll
          for (int nf = 0; nf < 4; ++nf)
            bfr[ks][nf] = frag64(Bb, wn + nf * 16 + l15, ks, lhi);
      }
      s16x8 af[2][2];
      #pragma unroll
      for (int i = 0; i < 2; ++i)
        #pragma unroll
        for (int ks = 0; ks < 2; ++ks)
          af[i][ks] = frag64(Ab, wm + (2 * q + i) * 16 + l15, ks, lhi);
      // staging: q0/q1 -> A halves of t+1 (other buffer, dead since (t-1,3));
      //          q2/q3 -> B halves of t+2 (this buffer's B, dead after (t,0))
      if (q == 0 && t + 1 < nt) stage_half(Ag, K, t + 1, 0, LBUF + ((t + 1) & 1) * 16384, wave, lane);
      if (q == 1 && t + 1 < nt) stage_half(Ag, K, t + 1, 1, LBUF + ((t + 1) & 1) * 16384, wave, lane);
      if (q == 2 && t + 2 < nt) stage_half(Bg, K, t + 2, 0, LBUF + 32768 + (t & 1) * 16384, wave, lane);
      if (q == 3 && t + 2 < nt) stage_half(Bg, K, t + 2, 1, LBUF + 32768 + (t & 1) * 16384, wave, lane);
      __builtin_amdgcn_sched_barrier(0);
      __builtin_amdgcn_s_barrier();
      asm volatile("s_waitcnt lgkmcnt(0)" ::: "memory");
      __builtin_amdgcn_sched_barrier(0);
      __builtin_amdgcn_s_setprio(1);
      #pragma unroll
      for (int i = 0; i < 2; ++i)
        #pragma unroll
        for (int nf = 0; nf < 4; ++nf)
          #pragma unroll
          for (int ks = 0; ks < 2; ++ks)
            acc[2 * q + i][nf] = MFMA16(af[i][ks], bfr[ks][nf], acc[2 * q + i][nf]);
      __builtin_amdgcn_s_setprio(0);
      if (q == 3){
        if (t < nt - 2)       asm volatile("s_waitcnt vmcnt(4)" ::: "memory");
        else if (t == nt - 2) asm volatile("s_waitcnt vmcnt(0)" ::: "memory");
        __builtin_amdgcn_sched_barrier(0);
      }
      __builtin_amdgcn_s_barrier();
    }
  }
  // ---- epilogue
  if (MODE == 2){
    float* dst = (float*)o0;
    #pragma unroll
    for (int mf = 0; mf < 8; ++mf){
      int rb = m0 + wm + mf * 16 + 4 * lhi;
      #pragma unroll
      for (int nf = 0; nf < 4; ++nf){
        int col = n0 + wn + nf * 16 + l15;
        #pragma unroll
        for (int r = 0; r < 4; ++r) dst[(size_t)(rb + r) * 1024 + col] = acc[mf][nf][r];
      }
    }
  } else {
    if (n0 < 2048){                                 // q or k, bf16 row-major ld=1024
      short* dst = (short*)(n0 < 1024 ? o0 : o1);
      int cb = (n0 & 1023) + wn;
      #pragma unroll
      for (int mf = 0; mf < 8; ++mf){
        int rb = m0 + wm + mf * 16 + 4 * lhi;
        #pragma unroll
        for (int nf = 0; nf < 4; ++nf){
          int col = cb + nf * 16 + l15;
          #pragma unroll
          for (int r = 0; r < 4; ++r) dst[(size_t)(rb + r) * 1024 + col] = f2bf(acc[mf][nf][r]);
        }
      }
    } else if (n0 < 4096){                          // v, transposed out [2048][8192]
      short* dst = (short*)o2;
      #pragma unroll
      for (int mf = 0; mf < 8; ++mf){
        int rb = m0 + wm + mf * 16 + 4 * lhi;
        #pragma unroll
        for (int nf = 0; nf < 4; ++nf){
          int e = (n0 - 2048) + wn + nf * 16 + l15;
          s16x4 pk;
          #pragma unroll
          for (int r = 0; r < 4; ++r) pk[r] = f2bf(acc[mf][nf][r]);
          *(s16x4*)&dst[(size_t)e * MROWS + rb] = pk;
        }
      }
    } else {                                        // g, bf16 row-major ld=2048
      short* dst = (short*)o3;
      int cb = (n0 - 4096) + wn;
      #pragma unroll
      for (int mf = 0; mf < 8; ++mf){
        int rb = m0 + wm + mf * 16 + 4 * lhi;
        #pragma unroll
        for (int nf = 0; nf < 4; ++nf){
          int col = cb + nf * 16 + l15;
          #pragma unroll
          for (int r = 0; r < 4; ++r) dst[(size_t)(rb + r) * 2048 + col] = f2bf(acc[mf][nf][r]);
        }
      }
    }
  }
}

// ---------------- retention state scan: S in MFMA accumulators, write bf16 ST[n] snapshots ----------------
// grid (8=db*eb, 8, 4); 256 thr. Block owns d-range 64 (db) x e-range 64 (eb).
__global__ __launch_bounds__(256) void ret_scan(const short* __restrict__ kT,
                                                const short* __restrict__ vT,
                                                short* __restrict__ ST){
  __shared__ alignas(16) short kbuf[3][4096];
  __shared__ alignas(16) short vbuf[3][4096];
  const int tid = threadIdx.x, wave = tid >> 6, lane = tid & 63;
  const int db = blockIdx.x & 1, eb = blockIdx.x >> 1;
  const int h = blockIdx.y, b = blockIdx.z;
  const int d0 = db * 64, e0 = eb * 64;
  const float lg = log2f(1.0f - exp2f(-(float)(5 + h)));
  const float gC = exp2f(64.0f * lg);
  f32x4 Sacc[4] = {};
  const int srow = wave * 8 + (lane >> 3);
  const int sc   = lane & 7;

  auto STAGE = [&](int n, int buf){
    size_t rowbase = (size_t)(b * T_LEN + n * 64);
    #pragma unroll
    for (int c = 0; c < 2; ++c){
      int r = c * 32 + srow;
      int gc = sc ^ (r & 7);
      GLOAD16(kT + (size_t)(h * 128 + d0 + r) * MROWS + rowbase + gc * 8,
              &kbuf[buf][c * 2048 + wave * 512]);
    }
    #pragma unroll
    for (int c = 0; c < 2; ++c){
      int r = c * 32 + srow;
      int gc = sc ^ (r & 7);
      GLOAD16(vT + (size_t)(h * 256 + e0 + r) * MROWS + rowbase + gc * 8,
              &vbuf[buf][c * 2048 + wave * 512]);
    }
  };

  STAGE(0, 0);
  STAGE(1, 1);
  for (int n = 0; n < NCHUNK; ++n){
    const int buf = n % 3;
    if (n + 2 < NCHUNK) STAGE(n + 2, (n + 2) % 3);      // 4 loads
    if (n > 0){                                          // 4 stores (snapshot BEFORE this chunk)
      size_t stb = (((size_t)n * 4 + b) * 8 + h) * 32768;
      int dbase = d0 + 16 * wave + 4 * (lane >> 4);
      #pragma unroll
      for (int nf = 0; nf < 4; ++nf){
        int e = e0 + nf * 16 + (lane & 15);
        s16x4 pk;
        #pragma unroll
        for (int r = 0; r < 4; ++r) pk[r] = f2bf(Sacc[nf][r]);
        *(s16x4*)&ST[stb + (size_t)e * 128 + dbase] = pk;
      }
    }
    // counted vmcnt: guarantee chunk-n loads complete; newer loads/stores stay outstanding
    if (n == 0)       asm volatile("s_waitcnt vmcnt(8)"  ::: "memory");
    else if (n < 30)  asm volatile("s_waitcnt vmcnt(12)" ::: "memory");
    else if (n == 30) asm volatile("s_waitcnt vmcnt(8)"  ::: "memory");
    else              asm volatile("s_waitcnt vmcnt(4)"  ::: "memory");
    __builtin_amdgcn_s_barrier();
    __builtin_amdgcn_sched_barrier(0);
    #pragma unroll
    for (int nf = 0; nf < 4; ++nf)
      #pragma unroll
      for (int r = 0; r < 4; ++r) Sacc[nf][r] *= gC;
    #pragma unroll
    for (int ks = 0; ks < 2; ++ks){
      int d = 16 * wave + (lane & 15);
      int chA = (ks * 4 + (lane >> 4)) ^ (d & 7);
      s16x8 af = *(const s16x8*)&kbuf[buf][d * 64 + chA * 8];
      #pragma unroll
      for (int nf = 0; nf < 4; ++nf){
        int e = nf * 16 + (lane & 15);
        int chB = (ks * 4 + (lane >> 4)) ^ (e & 7);
        s16x8 bv = *(const s16x8*)&vbuf[buf][e * 64 + chB * 8];
        Sacc[nf] = MFMA16(af, bv, Sacc[nf]);
      }
    }
    __builtin_amdgcn_s_barrier();
    __builtin_amdgcn_sched_barrier(0);
  }
}

// ---------------- fused per-chunk retention + RMS-norm + SiLU gate (reg-direct) ----------------
__global__ __launch_bounds__(256, 2) void ret_fused(const short* __restrict__ q,
                                                    const short* __restrict__ k,
                                                    const short* __restrict__ vT,
                                                    const short* __restrict__ ST,
                                                    const short* __restrict__ g,
                                                    const float* __restrict__ nw,
                                                    short* __restrict__ y){
  __shared__ alignas(16) short GS[16384];             // gate tile [64][256]
  __shared__ alignas(16) float SS[256];               // cross-wave sum-of-squares
  __shared__ alignas(16) short XS[16896];             // phase1: PS [64][72]; phase2: YT [64][264]
  short* PS = XS;
  short* YT = XS;
  const int tid = threadIdx.x, wave = tid >> 6, lane = tid & 63;
  const int l15 = lane & 15, lhi = lane >> 4;
  const int n = blockIdx.x, h = blockIdx.y, b = blockIdx.z;
  const size_t rowbase = (size_t)(b * T_LEN + n * 64);
  // ---- issue gate staging first (consumed in epilogue; drained by syncthreads)
  {
    int row = wave * 2 + (lane >> 5), sc32 = lane & 31;
    #pragma unroll
    for (int c = 0; c < 8; ++c){
      int r = c * 8 + row;
      GLOAD16(g + (rowbase + r) * 2048 + h * 256 + sc32 * 8, &GS[c * 2048 + wave * 512]);
    }
  }
  // ---- Q fragments (reused as P-phase B-operand AND o_inter A-operand)
  s16x8 Qf[4][4];
  #pragma unroll
  for (int rf = 0; rf < 4; ++rf)
    #pragma unroll
    for (int ks = 0; ks < 4; ++ks)
      Qf[rf][ks] = *(const s16x8*)&q[(rowbase + rf * 16 + l15) * 1024 + h * 128 + ks * 32 + lhi * 8];
  // ---- K fragments (P-phase A-operand; wave-specific j rows)
  s16x8 Kf[4];
  #pragma unroll
  for (int ks = 0; ks < 4; ++ks)
    Kf[ks] = *(const s16x8*)&k[(rowbase + wave * 16 + l15) * 1024 + h * 128 + ks * 32 + lhi * 8];
  // ---- P^T = k q'^T : D[j][i]; wave owns j in [16w,16w+16)
  f32x4 accP[4] = {};
  #pragma unroll
  for (int ks = 0; ks < 4; ++ks)
    #pragma unroll
    for (int nf = 0; nf < 4; ++nf)
      accP[nf] = MFMA16(Kf[ks], Qf[nf][ks], accP[nf]);
  const float lg = log2f(1.0f - exp2f(-(float)(5 + h)));
  {
    int jb = wave * 16 + 4 * lhi;
    float dj[4];
    #pragma unroll
    for (int r = 0; r < 4; ++r) dj[r] = exp2f(-(float)(jb + r + 1) * lg);
    #pragma unroll
    for (int nf = 0; nf < 4; ++nf){
      int i = nf * 16 + l15;
      s16x4 pk;
      #pragma unroll
      for (int r = 0; r < 4; ++r)
        pk[r] = f2bf((i >= jb + r) ? accP[nf][r] * dj[r] : 0.0f);
      *(s16x4*)&PS[i * 72 + jb] = pk;
    }
  }
  // ---- o_inter: acc = q'.S (ST fragments streamed global->reg); wave owns e in [64w,64w+64)
  f32x4 acc[4][4] = {};
  if (n){
    size_t stb = (((size_t)n * 4 + b) * 8 + h) * 32768;
    #pragma unroll
    for (int ks = 0; ks < 4; ++ks){
      s16x8 Sf[4];
      #pragma unroll
      for (int nf = 0; nf < 4; ++nf){
        int e = wave * 64 + nf * 16 + l15;
        Sf[nf] = *(const s16x8*)&ST[stb + (size_t)e * 128 + ks * 32 + lhi * 8];
      }
      #pragma unroll
      for (int mf = 0; mf < 4; ++mf)
        #pragma unroll
        for (int nf = 0; nf < 4; ++nf)
          acc[mf][nf] = MFMA16(Qf[mf][ks], Sf[nf], acc[mf][nf]);
    }
  }
  // ---- hoist V fragment loads above the PS barrier (latency hides under barrier wait)
  s16x8 Vf[2][4];
  #pragma unroll
  for (int ks2 = 0; ks2 < 2; ++ks2)
    #pragma unroll
    for (int nf = 0; nf < 4; ++nf){
      int e = wave * 64 + nf * 16 + l15;
      Vf[ks2][nf] = *(const s16x8*)&vT[(size_t)(h * 256 + e) * MROWS + rowbase + ks2 * 32 + lhi * 8];
    }
  __syncthreads();                                   // PS visible (also drains GS staging)
  // ---- o_intra: acc += P v  (P from LDS, V from regs)
  #pragma unroll
  for (int ks2 = 0; ks2 < 2; ++ks2){
    s16x8 Pf[4];
    #pragma unroll
    for (int mf = 0; mf < 4; ++mf)
      Pf[mf] = *(const s16x8*)&PS[(mf * 16 + l15) * 72 + ks2 * 32 + lhi * 8];
    #pragma unroll
    for (int mf = 0; mf < 4; ++mf)
      #pragma unroll
      for (int nf = 0; nf < 4; ++nf)
        acc[mf][nf] = MFMA16(Pf[mf], Vf[ks2][nf], acc[mf][nf]);
  }
  // ---- row-wise sum of squares (over e=256): intra-wave shuffle + cross-wave LDS
  float ssp[4][4];
  #pragma unroll
  for (int mf = 0; mf < 4; ++mf)
    #pragma unroll
    for (int r = 0; r < 4; ++r){
      float s = 0.f;
      #pragma unroll
      for (int nf = 0; nf < 4; ++nf) s += acc[mf][nf][r] * acc[mf][nf][r];
      #pragma unroll
      for (int off = 8; off >= 1; off >>= 1) s += __shfl_xor(s, off, 64);
      ssp[mf][r] = s;
    }
  if (l15 == 0){
    #pragma unroll
    for (int mf = 0; mf < 4; ++mf)
      #pragma unroll
      for (int r = 0; r < 4; ++r){
        int row = mf * 16 + 4 * lhi + r;
        SS[row * 4 + wave] = ssp[mf][r];
      }
  }
  __syncthreads();                                   // SS + GS ready; PS dead (YT aliases it)
  // ---- normalize + gate, write padded y tile
  #pragma unroll
  for (int mf = 0; mf < 4; ++mf){
    float rr[4];
    #pragma unroll
    for (int r = 0; r < 4; ++r){
      int row = mf * 16 + 4 * lhi + r;
      f32x4 s4 = *(const f32x4*)&SS[row * 4];
      float tot = s4[0] + s4[1] + s4[2] + s4[3];
      rr[r] = __builtin_amdgcn_rsqf(tot * (1.0f / 256.0f) + 1e-5f);
    }
    #pragma unroll
    for (int nf = 0; nf < 4; ++nf){
      int e = wave * 64 + nf * 16 + l15;
      float nwe = nw[e];
      #pragma unroll
      for (int r = 0; r < 4; ++r){
        int row = mf * 16 + 4 * lhi + r;
        float gf = bf2f(GS[row * 256 + e]);
        float sig = __builtin_amdgcn_rcpf(1.0f + exp2f(gf * -1.4426950408889634f));
        YT[row * 264 + e] = f2bf(acc[mf][nf][r] * rr[r] * nwe * gf * sig);
      }
    }
  }
  __syncthreads();
  // ---- coalesced copy out
  #pragma unroll
  for (int it = 0; it < 8; ++it){
    int flat = it * 2048 + tid * 8;
    int row = flat >> 8, e = flat & 255;
    s16x8 v = *(const s16x8*)&YT[row * 264 + e];
    *(s16x8*)&y[(rowbase + row) * 2048 + h * 256 + e] = v;
  }
}

// ---------------- host ----------------
extern "C" void kernel_launch(void* const* d_in, const int* in_sizes, int n_in,
                              void* d_out, int out_size, void* d_ws, size_t ws_size,
                              hipStream_t stream){
  const float* x  = (const float*)d_in[0];
  const float* Wq = (const float*)d_in[1];
  const float* Wk = (const float*)d_in[2];
  const float* Wv = (const float*)d_in[3];
  const float* Wg = (const float*)d_in[4];
  const float* Wo = (const float*)d_in[5];
  const float* nw = (const float*)d_in[6];
  float* out = (float*)d_out;

  // workspace layout (208 MiB total).
  // yb aliases [0, 32MB) = xb + WT + head of kTt — all dead before ret_fused writes it.
  // rope table aliases STb's n=0 slice (scan writes n>=1 only, fused reads n>=1 only).
  char* w = (char*)d_ws;
  short* xb  = (short*)w;               w += (size_t)8192 * 1024 * 2;   // 16 MB
  short* WT  = (short*)w;               w += (size_t)6144 * 1024 * 2;   // 12.6 MB (WqT|WkT|WvT|WgT)
  short* kTt = (short*)w;               w += (size_t)1024 * 8192 * 2;   // 16 MB (dead after ret_scan)
  short* qb  = (short*)w;               w += (size_t)8192 * 1024 * 2;   // 16 MB
  short* kb  = (short*)w;               w += (size_t)8192 * 1024 * 2;   // 16 MB
  short* vT  = (short*)w;               w += (size_t)2048 * 8192 * 2;   // 32 MB
  short* gb  = (short*)w;               w += (size_t)8192 * 2048 * 2;   // 32 MB
  short* STb = (short*)w;               w += (size_t)32 * 4 * 8 * 32768 * 2; // 64 MB
  short* WoT = (short*)w;               w += (size_t)1024 * 2048 * 2;   // 4 MB
  short* yb  = (short*)d_ws;                                            // alias, 32 MB
  float* tab = (float*)STb;                                             // alias, 1 MB (n=0 slice)

  cvt_f32_bf16<<<8192, 256, 0, stream>>>(x, xb, 8192 * 1024 / 4);
  dim3 tb(32, 8);
  tr_w<<<dim3(32, 32), tb, 0, stream>>>(Wq, WT,                       1024, 1024);
  tr_w<<<dim3(32, 32), tb, 0, stream>>>(Wk, WT + (size_t)1024 * 1024, 1024, 1024);
  tr_w<<<dim3(64, 32), tb, 0, stream>>>(Wv, WT + (size_t)2048 * 1024, 1024, 2048);
  tr_w<<<dim3(64, 32), tb, 0, stream>>>(Wg, WT + (size_t)4096 * 1024, 1024, 2048);
  tr_w<<<dim3(32, 64), tb, 0, stream>>>(Wo, WoT,                      2048, 1024);
  rope_table<<<512, 256, 0, stream>>>(tab);

  // fused q|k|v|g projection: [8192][1024] x [6144][1024]^T, 8-phase 256^2 schedule
  gemm256<3><<<768, 512, 0, stream>>>(xb, WT, qb, kb, vT, gb, 1024, 16);

  rope_inplace<<<16384, 256, 0, stream>>>(qb, tab, 0.08838834764831845f, 1);  // DK^-0.5 + dec_q
  rope_inplace<<<16384, 256, 0, stream>>>(kb, tab, 1.0f, 0);
  tr_k_decay<<<dim3(32, 256), tb, 0, stream>>>(kb, kTt);

  ret_scan <<<dim3(8, 8, 4),  256, 0, stream>>>(kTt, vT, STb);
  ret_fused<<<dim3(32, 8, 4), 256, 0, stream>>>(qb, kb, vT, STb, gb, nw, yb);

  // out-projection: [8192][2048] x [1024][2048]^T -> f32 [8192][1024]
  gemm256<2><<<128, 512, 0, stream>>>(yb, WoT, out, nullptr, nullptr, nullptr, 2048, 32);
}

// Round 5
// 288.319 us; speedup vs baseline: 1.2314x; 1.0652x over previous
//
#include <hip/hip_runtime.h>
#include <hip/hip_bf16.h>
#include <cstdint>
#include <cstddef>

using f32x4 = __attribute__((ext_vector_type(4))) float;
using s16x8 = __attribute__((ext_vector_type(8))) short;
using s16x4 = __attribute__((ext_vector_type(4))) short;

#define DEVINL __device__ __forceinline__

static constexpr int T_LEN  = 2048;
static constexpr int MROWS  = 8192;   // B*T
static constexpr int NCHUNK = 32;     // T / 64

DEVINL float bf2f(short s){
  unsigned u = ((unsigned)(unsigned short)s) << 16;
  return __builtin_bit_cast(float, u);
}
DEVINL short f2bf(float f){
  unsigned u = __builtin_bit_cast(unsigned, f);
  u = (u + 0x7fffu + ((u >> 16) & 1u)) >> 16;
  return (short)(unsigned short)u;
}

// async global->LDS, 16B per lane; LDS dest must be wave-uniform base (+lane*16 implicit)
#define GLOAD16(gp, lp) \
  __builtin_amdgcn_global_load_lds((__attribute__((address_space(1))) void*)(gp), \
                                   (__attribute__((address_space(3))) void*)(lp), 16, 0, 0)

#define MFMA16(a, b, c) __builtin_amdgcn_mfma_f32_16x16x32_bf16((a), (b), (c), 0, 0, 0)

// ---------------- elementwise f32 -> bf16 ----------------
__global__ __launch_bounds__(256) void cvt_f32_bf16(const float* __restrict__ in,
                                                    short* __restrict__ out, int n4){
  int i = blockIdx.x * 256 + threadIdx.x;
  if (i >= n4) return;
  float4 v = ((const float4*)in)[i];
  short4 o;
  o.x = f2bf(v.x); o.y = f2bf(v.y); o.z = f2bf(v.z); o.w = f2bf(v.w);
  ((short4*)out)[i] = o;
}

// ---------------- transpose f32 [R][C] -> bf16 [C][R] ----------------
__global__ __launch_bounds__(256) void tr_w(const float* __restrict__ in,
                                            short* __restrict__ out, int R, int C){
  __shared__ float tile[32][33];
  int c0 = blockIdx.x * 32, r0 = blockIdx.y * 32;
  int tx = threadIdx.x, ty = threadIdx.y;           // (32,8)
  #pragma unroll
  for (int i = 0; i < 4; ++i){
    int r = ty + i * 8;
    tile[r][tx] = in[(size_t)(r0 + r) * C + c0 + tx];
  }
  __syncthreads();
  #pragma unroll
  for (int i = 0; i < 4; ++i){
    int c = ty + i * 8;
    out[(size_t)(c0 + c) * R + r0 + tx] = f2bf(tile[tx][c]);
  }
}

// ------- transpose bf16 k [8192][1024] -> kT [1024][8192], baking dec_k = gamma^(63-j) -------
__global__ __launch_bounds__(256) void tr_k_decay(const short* __restrict__ in,
                                                  short* __restrict__ out){
  __shared__ float tile[32][33];
  int c0 = blockIdx.x * 32, r0 = blockIdx.y * 32;   // c over 1024 feature cols, r over 8192 rows
  int tx = threadIdx.x, ty = threadIdx.y;
  #pragma unroll
  for (int i = 0; i < 4; ++i){
    int r = ty + i * 8;
    tile[r][tx] = bf2f(in[(size_t)(r0 + r) * 1024 + c0 + tx]);
  }
  __syncthreads();
  #pragma unroll
  for (int i = 0; i < 4; ++i){
    int c  = c0 + ty + i * 8;
    int h  = c >> 7;
    float lg = log2f(1.0f - exp2f(-(float)(5 + h)));
    int srow = r0 + tx;
    int j = srow & 63;
    float dec = exp2f((float)(63 - j) * lg);
    out[(size_t)c * MROWS + srow] = f2bf(tile[tx][ty + i * 8] * dec);
  }
}

// ---------------- rope cos/sin table [2048][64] float2 ----------------
__global__ __launch_bounds__(256) void rope_table(float* __restrict__ tab){
  int i = blockIdx.x * 256 + threadIdx.x;           // t*64+d, 131072 total
  int t = i >> 6, d = i & 63;
  float inv = exp2f(-(float)d * (13.287712379549449f / 64.0f));  // 10000^(-d/64)
  float f = (float)t * inv;
  float s, c;
  sincosf(f, &s, &c);
  tab[2 * i]     = c;
  tab[2 * i + 1] = s;
}

// ------- RoPE in-place on bf16 [8192][1024]; optional dec_q = gamma^((t%64)+1) bake (q only) -------
__global__ __launch_bounds__(256) void rope_inplace(short* __restrict__ qk,
                                                    const float* __restrict__ tab,
                                                    float scale, int bake){
  int idx = blockIdx.x * 256 + threadIdx.x;         // 8192 * 512 threads
  int bt  = idx >> 9, rem = idx & 511;
  int h   = rem >> 6, d = rem & 63;
  int t   = bt & (T_LEN - 1);
  float2 cs = ((const float2*)tab)[t * 64 + d];
  float mult = scale;
  if (bake){
    float lg = log2f(1.0f - exp2f(-(float)(5 + h)));
    mult *= exp2f((float)((t & 63) + 1) * lg);      // gamma^(i+1)
  }
  size_t base = (size_t)bt * 1024 + h * 128 + d;
  float x1 = bf2f(qk[base]), x2 = bf2f(qk[base + 64]);
  qk[base]      = f2bf((x1 * cs.x - x2 * cs.y) * mult);
  qk[base + 64] = f2bf((x2 * cs.x + x1 * cs.y) * mult);
}

// ======= 8-phase GEMM, BK=64, 8 waves, 2-tile-deep prefetch both operands =======
// C[m][n] = sum_k A[m][k] * Bt[n][k].
// MODE 2: BM=128, f32 row-major out (N=1024), o0.
// MODE 3: BM=256, fused projection epilogue (N=6144):
//   n0 in [0,1024) -> o0=qb bf16 [8192][1024]; [1024,2048) -> o1=kb; [2048,4096) -> o2=vT
//   transposed [2048][8192]; [4096,6144) -> o3=gb [8192][2048].
// A triple-buffered (A(t+2) staged q0/q1), B double-buffered (B(t+2) staged q2/q3).
// Steady-state vmcnt leaves exactly the t+2 loads (8 for BM=256, 6 for BM=128) in flight.
DEVINL s16x8 frag64(const short* buf, int row, int ks, int lhi){
  int ch = (ks * 4 + lhi) ^ (row & 7);
  return *(const s16x8*)&buf[row * 64 + ch * 8];
}

template<int MODE>
__global__ __launch_bounds__(512, 2) void gemm256(const short* __restrict__ A,
                                                  const short* __restrict__ Bt,
                                                  void* __restrict__ o0, void* __restrict__ o1,
                                                  void* __restrict__ o2, void* __restrict__ o3,
                                                  int K, int nt, int NT){
  constexpr int BM   = (MODE == 2 ? 128 : 256);
  constexpr int ABUF = BM * 64;                     // shorts per A buffer
  constexpr int MF   = BM / 32;                     // acc rows per wave (4 or 8)
  constexpr int RPP  = MF / 4;                      // acc rows per phase (1 or 2)
  __shared__ alignas(16) short LBUF[3 * ABUF + 2 * 16384];
  short* const BB = LBUF + 3 * ABUF;
  const int tid = threadIdx.x, wave = tid >> 6, lane = tid & 63;
  const int l15 = lane & 15, lhi = lane >> 4;
  const int wm = (wave >> 2) * (BM / 2), wn = (wave & 3) * 64;
  // XCD group-major swizzle: per XCD walk m within group of MG (A stays L2-resident), n outer
  const int MG  = (gridDim.x >> 3) / NT;
  const int xcd = blockIdx.x & 7, idx = blockIdx.x >> 3;
  const int mi  = idx % MG, nn = idx / MG;
  const int m0  = (xcd * MG + mi) * BM, n0 = nn * 256;
  const short* Ag = A + (size_t)m0 * K;
  const short* Bg = Bt + (size_t)n0 * K;
  const int sr = lane >> 3;
  const int gc = ((lane & 7) ^ sr) * 8;             // pre-swizzled source chunk
  f32x4 acc[MF][4] = {};

  auto stageA = [&](int t, int half){
    short* lb = LBUF + (t % 3) * ABUF;
    size_t k0 = (size_t)t * 64;
    if constexpr (BM == 256){
      #pragma unroll
      for (int c = 0; c < 2; ++c){
        int r0 = half * 128 + c * 64;
        GLOAD16(Ag + (size_t)(r0 + wave * 8 + sr) * K + k0 + gc, lb + (r0 + wave * 8) * 64);
      }
    } else {
      int r0 = half * 64;
      GLOAD16(Ag + (size_t)(r0 + wave * 8 + sr) * K + k0 + gc, lb + (r0 + wave * 8) * 64);
    }
  };
  auto stageB = [&](int t, int half){
    short* lb = BB + (t & 1) * 16384;
    size_t k0 = (size_t)t * 64;
    #pragma unroll
    for (int c = 0; c < 2; ++c){
      int r0 = half * 128 + c * 64;
      GLOAD16(Bg + (size_t)(r0 + wave * 8 + sr) * K + k0 + gc, lb + (r0 + wave * 8) * 64);
    }
  };

  // ---- prologue: tiles 0 and 1, both operands; drain tile0, keep tile1 in flight
  stageA(0, 0); stageA(0, 1); stageB(0, 0); stageB(0, 1);
  stageA(1, 0); stageA(1, 1); stageB(1, 0); stageB(1, 1);
  if constexpr (BM == 256) asm volatile("s_waitcnt vmcnt(8)" ::: "memory");
  else                     asm volatile("s_waitcnt vmcnt(6)" ::: "memory");
  __builtin_amdgcn_sched_barrier(0);
  __builtin_amdgcn_s_barrier();

  for (int t = 0; t < nt; ++t){
    const short* Ab = LBUF + (t % 3) * ABUF;
    const short* Bb = BB + (t & 1) * 16384;
    s16x8 bfr[2][4];
    #pragma unroll
    for (int q = 0; q < 4; ++q){
      if (q == 0){
        #pragma unroll
        for (int ks = 0; ks < 2; ++ks)
          #pragma unroll
          for (int nf = 0; nf < 4; ++nf)
            bfr[ks][nf] = frag64(Bb, wn + nf * 16 + l15, ks, lhi);
      }
      s16x8 af[RPP][2];
      #pragma unroll
      for (int i = 0; i < RPP; ++i)
        #pragma unroll
        for (int ks = 0; ks < 2; ++ks)
          af[i][ks] = frag64(Ab, wm + (RPP * q + i) * 16 + l15, ks, lhi);
      if (t + 2 < nt){
        if (q == 0) stageA(t + 2, 0);
        if (q == 1) stageA(t + 2, 1);
        if (q == 2) stageB(t + 2, 0);
        if (q == 3) stageB(t + 2, 1);
      }
      __builtin_amdgcn_sched_barrier(0);
      __builtin_amdgcn_s_barrier();
      asm volatile("s_waitcnt lgkmcnt(0)" ::: "memory");
      __builtin_amdgcn_sched_barrier(0);
      __builtin_amdgcn_s_setprio(1);
      #pragma unroll
      for (int i = 0; i < RPP; ++i)
        #pragma unroll
        for (int nf = 0; nf < 4; ++nf)
          #pragma unroll
          for (int ks = 0; ks < 2; ++ks)
            acc[RPP * q + i][nf] = MFMA16(af[i][ks], bfr[ks][nf], acc[RPP * q + i][nf]);
      __builtin_amdgcn_s_setprio(0);
      if (q == 3){
        if (t < nt - 2){
          if constexpr (BM == 256) asm volatile("s_waitcnt vmcnt(8)" ::: "memory");
          else                     asm volatile("s_waitcnt vmcnt(6)" ::: "memory");
        } else if (t == nt - 2){
          asm volatile("s_waitcnt vmcnt(0)" ::: "memory");
        }
        __builtin_amdgcn_sched_barrier(0);
      }
      __builtin_amdgcn_s_barrier();
    }
  }
  // ---- epilogue
  if (MODE == 2){
    float* dst = (float*)o0;
    #pragma unroll
    for (int mf = 0; mf < MF; ++mf){
      int rb = m0 + wm + mf * 16 + 4 * lhi;
      #pragma unroll
      for (int nf = 0; nf < 4; ++nf){
        int col = n0 + wn + nf * 16 + l15;
        #pragma unroll
        for (int r = 0; r < 4; ++r) dst[(size_t)(rb + r) * 1024 + col] = acc[mf][nf][r];
      }
    }
  } else {
    if (n0 < 2048){                                 // q or k, bf16 row-major ld=1024
      short* dst = (short*)(n0 < 1024 ? o0 : o1);
      int cb = (n0 & 1023) + wn;
      #pragma unroll
      for (int mf = 0; mf < MF; ++mf){
        int rb = m0 + wm + mf * 16 + 4 * lhi;
        #pragma unroll
        for (int nf = 0; nf < 4; ++nf){
          int col = cb + nf * 16 + l15;
          #pragma unroll
          for (int r = 0; r < 4; ++r) dst[(size_t)(rb + r) * 1024 + col] = f2bf(acc[mf][nf][r]);
        }
      }
    } else if (n0 < 4096){                          // v, transposed out [2048][8192]
      short* dst = (short*)o2;
      #pragma unroll
      for (int mf = 0; mf < MF; ++mf){
        int rb = m0 + wm + mf * 16 + 4 * lhi;
        #pragma unroll
        for (int nf = 0; nf < 4; ++nf){
          int e = (n0 - 2048) + wn + nf * 16 + l15;
          s16x4 pk;
          #pragma unroll
          for (int r = 0; r < 4; ++r) pk[r] = f2bf(acc[mf][nf][r]);
          *(s16x4*)&dst[(size_t)e * MROWS + rb] = pk;
        }
      }
    } else {                                        // g, bf16 row-major ld=2048
      short* dst = (short*)o3;
      int cb = (n0 - 4096) + wn;
      #pragma unroll
      for (int mf = 0; mf < MF; ++mf){
        int rb = m0 + wm + mf * 16 + 4 * lhi;
        #pragma unroll
        for (int nf = 0; nf < 4; ++nf){
          int col = cb + nf * 16 + l15;
          #pragma unroll
          for (int r = 0; r < 4; ++r) dst[(size_t)(rb + r) * 2048 + col] = f2bf(acc[mf][nf][r]);
        }
      }
    }
  }
}

// ---------------- retention state scan: S in MFMA accumulators, write bf16 ST[n] snapshots ----------------
// grid (8=db*eb, 8, 4); 256 thr. Block owns d-range 64 (db) x e-range 64 (eb).
__global__ __launch_bounds__(256) void ret_scan(const short* __restrict__ kT,
                                                const short* __restrict__ vT,
                                                short* __restrict__ ST){
  __shared__ alignas(16) short kbuf[3][4096];
  __shared__ alignas(16) short vbuf[3][4096];
  const int tid = threadIdx.x, wave = tid >> 6, lane = tid & 63;
  const int db = blockIdx.x & 1, eb = blockIdx.x >> 1;
  const int h = blockIdx.y, b = blockIdx.z;
  const int d0 = db * 64, e0 = eb * 64;
  const float lg = log2f(1.0f - exp2f(-(float)(5 + h)));
  const float gC = exp2f(64.0f * lg);
  f32x4 Sacc[4] = {};
  const int srow = wave * 8 + (lane >> 3);
  const int sc   = lane & 7;

  auto STAGE = [&](int n, int buf){
    size_t rowbase = (size_t)(b * T_LEN + n * 64);
    #pragma unroll
    for (int c = 0; c < 2; ++c){
      int r = c * 32 + srow;
      int gc = sc ^ (r & 7);
      GLOAD16(kT + (size_t)(h * 128 + d0 + r) * MROWS + rowbase + gc * 8,
              &kbuf[buf][c * 2048 + wave * 512]);
    }
    #pragma unroll
    for (int c = 0; c < 2; ++c){
      int r = c * 32 + srow;
      int gc = sc ^ (r & 7);
      GLOAD16(vT + (size_t)(h * 256 + e0 + r) * MROWS + rowbase + gc * 8,
              &vbuf[buf][c * 2048 + wave * 512]);
    }
  };

  STAGE(0, 0);
  STAGE(1, 1);
  for (int n = 0; n < NCHUNK; ++n){
    const int buf = n % 3;
    if (n + 2 < NCHUNK) STAGE(n + 2, (n + 2) % 3);      // 4 loads
    if (n > 0){                                          // 4 stores (snapshot BEFORE this chunk)
      size_t stb = (((size_t)n * 4 + b) * 8 + h) * 32768;
      int dbase = d0 + 16 * wave + 4 * (lane >> 4);
      #pragma unroll
      for (int nf = 0; nf < 4; ++nf){
        int e = e0 + nf * 16 + (lane & 15);
        s16x4 pk;
        #pragma unroll
        for (int r = 0; r < 4; ++r) pk[r] = f2bf(Sacc[nf][r]);
        *(s16x4*)&ST[stb + (size_t)e * 128 + dbase] = pk;
      }
    }
    // counted vmcnt: guarantee chunk-n loads complete; newer loads/stores stay outstanding
    if (n == 0)       asm volatile("s_waitcnt vmcnt(8)"  ::: "memory");
    else if (n < 30)  asm volatile("s_waitcnt vmcnt(12)" ::: "memory");
    else if (n == 30) asm volatile("s_waitcnt vmcnt(8)"  ::: "memory");
    else              asm volatile("s_waitcnt vmcnt(4)"  ::: "memory");
    __builtin_amdgcn_s_barrier();
    __builtin_amdgcn_sched_barrier(0);
    #pragma unroll
    for (int nf = 0; nf < 4; ++nf)
      #pragma unroll
      for (int r = 0; r < 4; ++r) Sacc[nf][r] *= gC;
    #pragma unroll
    for (int ks = 0; ks < 2; ++ks){
      int d = 16 * wave + (lane & 15);
      int chA = (ks * 4 + (lane >> 4)) ^ (d & 7);
      s16x8 af = *(const s16x8*)&kbuf[buf][d * 64 + chA * 8];
      #pragma unroll
      for (int nf = 0; nf < 4; ++nf){
        int e = nf * 16 + (lane & 15);
        int chB = (ks * 4 + (lane >> 4)) ^ (e & 7);
        s16x8 bv = *(const s16x8*)&vbuf[buf][e * 64 + chB * 8];
        Sacc[nf] = MFMA16(af, bv, Sacc[nf]);
      }
    }
    __builtin_amdgcn_s_barrier();
    __builtin_amdgcn_sched_barrier(0);
  }
}

// ---------------- fused per-chunk retention + RMS-norm + SiLU gate (reg-direct) ----------------
__global__ __launch_bounds__(256, 2) void ret_fused(const short* __restrict__ q,
                                                    const short* __restrict__ k,
                                                    const short* __restrict__ vT,
                                                    const short* __restrict__ ST,
                                                    const short* __restrict__ g,
                                                    const float* __restrict__ nw,
                                                    short* __restrict__ y){
  __shared__ alignas(16) short GS[16384];             // gate tile [64][256]
  __shared__ alignas(16) float SS[256];               // cross-wave sum-of-squares
  __shared__ alignas(16) short XS[16896];             // phase1: PS [64][72]; phase2: YT [64][264]
  short* PS = XS;
  short* YT = XS;
  const int tid = threadIdx.x, wave = tid >> 6, lane = tid & 63;
  const int l15 = lane & 15, lhi = lane >> 4;
  const int n = blockIdx.x, h = blockIdx.y, b = blockIdx.z;
  const size_t rowbase = (size_t)(b * T_LEN + n * 64);
  // ---- issue gate staging first (consumed in epilogue; drained by syncthreads)
  {
    int row = wave * 2 + (lane >> 5), sc32 = lane & 31;
    #pragma unroll
    for (int c = 0; c < 8; ++c){
      int r = c * 8 + row;
      GLOAD16(g + (rowbase + r) * 2048 + h * 256 + sc32 * 8, &GS[c * 2048 + wave * 512]);
    }
  }
  // ---- Q fragments (reused as P-phase B-operand AND o_inter A-operand)
  s16x8 Qf[4][4];
  #pragma unroll
  for (int rf = 0; rf < 4; ++rf)
    #pragma unroll
    for (int ks = 0; ks < 4; ++ks)
      Qf[rf][ks] = *(const s16x8*)&q[(rowbase + rf * 16 + l15) * 1024 + h * 128 + ks * 32 + lhi * 8];
  // ---- K fragments (P-phase A-operand; wave-specific j rows)
  s16x8 Kf[4];
  #pragma unroll
  for (int ks = 0; ks < 4; ++ks)
    Kf[ks] = *(const s16x8*)&k[(rowbase + wave * 16 + l15) * 1024 + h * 128 + ks * 32 + lhi * 8];
  // ---- P^T = k q'^T : D[j][i]; wave owns j in [16w,16w+16)
  f32x4 accP[4] = {};
  #pragma unroll
  for (int ks = 0; ks < 4; ++ks)
    #pragma unroll
    for (int nf = 0; nf < 4; ++nf)
      accP[nf] = MFMA16(Kf[ks], Qf[nf][ks], accP[nf]);
  const float lg = log2f(1.0f - exp2f(-(float)(5 + h)));
  {
    int jb = wave * 16 + 4 * lhi;
    float dj[4];
    #pragma unroll
    for (int r = 0; r < 4; ++r) dj[r] = exp2f(-(float)(jb + r + 1) * lg);
    #pragma unroll
    for (int nf = 0; nf < 4; ++nf){
      int i = nf * 16 + l15;
      s16x4 pk;
      #pragma unroll
      for (int r = 0; r < 4; ++r)
        pk[r] = f2bf((i >= jb + r) ? accP[nf][r] * dj[r] : 0.0f);
      *(s16x4*)&PS[i * 72 + jb] = pk;
    }
  }
  // ---- o_inter: acc = q'.S (ST fragments streamed global->reg); wave owns e in [64w,64w+64)
  f32x4 acc[4][4] = {};
  if (n){
    size_t stb = (((size_t)n * 4 + b) * 8 + h) * 32768;
    #pragma unroll
    for (int ks = 0; ks < 4; ++ks){
      s16x8 Sf[4];
      #pragma unroll
      for (int nf = 0; nf < 4; ++nf){
        int e = wave * 64 + nf * 16 + l15;
        Sf[nf] = *(const s16x8*)&ST[stb + (size_t)e * 128 + ks * 32 + lhi * 8];
      }
      #pragma unroll
      for (int mf = 0; mf < 4; ++mf)
        #pragma unroll
        for (int nf = 0; nf < 4; ++nf)
          acc[mf][nf] = MFMA16(Qf[mf][ks], Sf[nf], acc[mf][nf]);
    }
  }
  // ---- hoist V fragment loads above the PS barrier (latency hides under barrier wait)
  s16x8 Vf[2][4];
  #pragma unroll
  for (int ks2 = 0; ks2 < 2; ++ks2)
    #pragma unroll
    for (int nf = 0; nf < 4; ++nf){
      int e = wave * 64 + nf * 16 + l15;
      Vf[ks2][nf] = *(const s16x8*)&vT[(size_t)(h * 256 + e) * MROWS + rowbase + ks2 * 32 + lhi * 8];
    }
  __syncthreads();                                   // PS visible (also drains GS staging)
  // ---- o_intra: acc += P v  (P from LDS, V from regs)
  #pragma unroll
  for (int ks2 = 0; ks2 < 2; ++ks2){
    s16x8 Pf[4];
    #pragma unroll
    for (int mf = 0; mf < 4; ++mf)
      Pf[mf] = *(const s16x8*)&PS[(mf * 16 + l15) * 72 + ks2 * 32 + lhi * 8];
    #pragma unroll
    for (int mf = 0; mf < 4; ++mf)
      #pragma unroll
      for (int nf = 0; nf < 4; ++nf)
        acc[mf][nf] = MFMA16(Pf[mf], Vf[ks2][nf], acc[mf][nf]);
  }
  // ---- row-wise sum of squares (over e=256): intra-wave shuffle + cross-wave LDS
  float ssp[4][4];
  #pragma unroll
  for (int mf = 0; mf < 4; ++mf)
    #pragma unroll
    for (int r = 0; r < 4; ++r){
      float s = 0.f;
      #pragma unroll
      for (int nf = 0; nf < 4; ++nf) s += acc[mf][nf][r] * acc[mf][nf][r];
      #pragma unroll
      for (int off = 8; off >= 1; off >>= 1) s += __shfl_xor(s, off, 64);
      ssp[mf][r] = s;
    }
  if (l15 == 0){
    #pragma unroll
    for (int mf = 0; mf < 4; ++mf)
      #pragma unroll
      for (int r = 0; r < 4; ++r){
        int row = mf * 16 + 4 * lhi + r;
        SS[row * 4 + wave] = ssp[mf][r];
      }
  }
  __syncthreads();                                   // SS + GS ready; PS dead (YT aliases it)
  // ---- normalize + gate, write padded y tile
  #pragma unroll
  for (int mf = 0; mf < 4; ++mf){
    float rr[4];
    #pragma unroll
    for (int r = 0; r < 4; ++r){
      int row = mf * 16 + 4 * lhi + r;
      f32x4 s4 = *(const f32x4*)&SS[row * 4];
      float tot = s4[0] + s4[1] + s4[2] + s4[3];
      rr[r] = __builtin_amdgcn_rsqf(tot * (1.0f / 256.0f) + 1e-5f);
    }
    #pragma unroll
    for (int nf = 0; nf < 4; ++nf){
      int e = wave * 64 + nf * 16 + l15;
      float nwe = nw[e];
      #pragma unroll
      for (int r = 0; r < 4; ++r){
        int row = mf * 16 + 4 * lhi + r;
        float gf = bf2f(GS[row * 256 + e]);
        float sig = __builtin_amdgcn_rcpf(1.0f + exp2f(gf * -1.4426950408889634f));
        YT[row * 264 + e] = f2bf(acc[mf][nf][r] * rr[r] * nwe * gf * sig);
      }
    }
  }
  __syncthreads();
  // ---- coalesced copy out
  #pragma unroll
  for (int it = 0; it < 8; ++it){
    int flat = it * 2048 + tid * 8;
    int row = flat >> 8, e = flat & 255;
    s16x8 v = *(const s16x8*)&YT[row * 264 + e];
    *(s16x8*)&y[(rowbase + row) * 2048 + h * 256 + e] = v;
  }
}

// ---------------- host ----------------
extern "C" void kernel_launch(void* const* d_in, const int* in_sizes, int n_in,
                              void* d_out, int out_size, void* d_ws, size_t ws_size,
                              hipStream_t stream){
  const float* x  = (const float*)d_in[0];
  const float* Wq = (const float*)d_in[1];
  const float* Wk = (const float*)d_in[2];
  const float* Wv = (const float*)d_in[3];
  const float* Wg = (const float*)d_in[4];
  const float* Wo = (const float*)d_in[5];
  const float* nw = (const float*)d_in[6];
  float* out = (float*)d_out;

  // workspace layout (208 MiB total).
  // yb aliases [0, 32MB) = xb + WT + head of kTt — all dead before ret_fused writes it.
  // rope table aliases STb's n=0 slice (scan writes n>=1 only, fused reads n>=1 only).
  char* w = (char*)d_ws;
  short* xb  = (short*)w;               w += (size_t)8192 * 1024 * 2;   // 16 MB
  short* WT  = (short*)w;               w += (size_t)6144 * 1024 * 2;   // 12.6 MB (WqT|WkT|WvT|WgT)
  short* kTt = (short*)w;               w += (size_t)1024 * 8192 * 2;   // 16 MB (dead after ret_scan)
  short* qb  = (short*)w;               w += (size_t)8192 * 1024 * 2;   // 16 MB
  short* kb  = (short*)w;               w += (size_t)8192 * 1024 * 2;   // 16 MB
  short* vT  = (short*)w;               w += (size_t)2048 * 8192 * 2;   // 32 MB
  short* gb  = (short*)w;               w += (size_t)8192 * 2048 * 2;   // 32 MB
  short* STb = (short*)w;               w += (size_t)32 * 4 * 8 * 32768 * 2; // 64 MB
  short* WoT = (short*)w;               w += (size_t)1024 * 2048 * 2;   // 4 MB
  short* yb  = (short*)d_ws;                                            // alias, 32 MB
  float* tab = (float*)STb;                                             // alias, 1 MB (n=0 slice)

  cvt_f32_bf16<<<8192, 256, 0, stream>>>(x, xb, 8192 * 1024 / 4);
  dim3 tb(32, 8);
  tr_w<<<dim3(32, 32), tb, 0, stream>>>(Wq, WT,                       1024, 1024);
  tr_w<<<dim3(32, 32), tb, 0, stream>>>(Wk, WT + (size_t)1024 * 1024, 1024, 1024);
  tr_w<<<dim3(64, 32), tb, 0, stream>>>(Wv, WT + (size_t)2048 * 1024, 1024, 2048);
  tr_w<<<dim3(64, 32), tb, 0, stream>>>(Wg, WT + (size_t)4096 * 1024, 1024, 2048);
  tr_w<<<dim3(32, 64), tb, 0, stream>>>(Wo, WoT,                      2048, 1024);
  rope_table<<<512, 256, 0, stream>>>(tab);

  // fused q|k|v|g projection: [8192][1024] x [6144][1024]^T, 256^2 8-phase, 2-deep prefetch
  gemm256<3><<<768, 512, 0, stream>>>(xb, WT, qb, kb, vT, gb, 1024, 16, 24);

  rope_inplace<<<16384, 256, 0, stream>>>(qb, tab, 0.08838834764831845f, 1);  // DK^-0.5 + dec_q
  rope_inplace<<<16384, 256, 0, stream>>>(kb, tab, 1.0f, 0);
  tr_k_decay<<<dim3(32, 256), tb, 0, stream>>>(kb, kTt);

  ret_scan <<<dim3(8, 8, 4),  256, 0, stream>>>(kTt, vT, STb);
  ret_fused<<<dim3(32, 8, 4), 256, 0, stream>>>(qb, kb, vT, STb, gb, nw, yb);

  // out-projection: [8192][2048] x [1024][2048]^T -> f32 [8192][1024], BM=128, full grid
  gemm256<2><<<256, 512, 0, stream>>>(yb, WoT, out, nullptr, nullptr, nullptr, 2048, 32, 4);
}